// Round 9
// baseline (219.178 us; speedup 1.0000x reference)
//
#include <hip/hip_runtime.h>
#include <hip/hip_bf16.h>
#include <hip/hip_cooperative_groups.h>

namespace cg = cooperative_groups;

#define B_ 16
#define T_ 32
#define NS_ 10
#define D_ 128
#define ST_ 512
#define V_ 32000
#define NCHAIN 160
#define NBLK 256          // == CU count: cooperative co-residency guaranteed

using short8  = __attribute__((ext_vector_type(8))) short;
using f32x4   = __attribute__((ext_vector_type(4))) float;
using half8   = __attribute__((ext_vector_type(8))) _Float16;
using half2v  = __attribute__((ext_vector_type(2))) _Float16;

__device__ __forceinline__ unsigned short f2bf(float f){
  unsigned u = __float_as_uint(f);
  u += 0x7FFFu + ((u >> 16) & 1u);          // RNE to bf16
  return (unsigned short)(u >> 16);
}
__device__ __forceinline__ unsigned packbf(float a, float b){
  return ((unsigned)f2bf(b) << 16) | (unsigned)f2bf(a);
}
__device__ __forceinline__ unsigned short f2h(float f){
  return __builtin_bit_cast(unsigned short, (_Float16)f);
}
__device__ __forceinline__ float h2f(unsigned u, int hi){
  half2v h = __builtin_bit_cast(half2v, u);
  return (float)h[hi];
}
__device__ __forceinline__ float readlane_f(float v, int lane){
  return __int_as_float(__builtin_amdgcn_readlane(__float_as_int(v), lane));
}

// wave64 inclusive scan via DPP: 6 ops
#define DPPADD(x, ctrl, rm) { \
  int _t = __builtin_amdgcn_update_dpp(0, __float_as_int(x), ctrl, rm, 0xf, true); \
  x += __int_as_float(_t); }

// ---------------------------------------------------------------------------
// ONE kernel, 3 phases. coop=1: single cooperative launch, grid.sync between
// phases. coop=0 fallback: launched 3x with phase = 1 / 2 / 4.
//  P1 (bit0): blocks 0..191 tables; 192..207 per-batch init.
//  P2 (bit1): blocks 0..159 scan chains; 160..255 logz (grid-stride 250 tiles).
//  P3 (bit2): blocks 0..127 dots.
// ---------------------------------------------------------------------------
__global__ __launch_bounds__(256) void fused_kernel(
    const int* __restrict__ zi, const int* __restrict__ y,
    const float* __restrict__ rd, const float* __restrict__ latent,
    const float* __restrict__ prefW, const float* __restrict__ prefB,
    const float* __restrict__ move, const float* __restrict__ vw,
    const float* __restrict__ vb,
    unsigned short* __restrict__ Hh, unsigned short* __restrict__ Lh,
    unsigned short* __restrict__ Gh, float2* __restrict__ SM,
    float* __restrict__ HU0, float* __restrict__ LU0, float* __restrict__ D0,
    float2* __restrict__ S0, float* __restrict__ partial,
    int* __restrict__ whichOut, unsigned* __restrict__ mbf,
    float* __restrict__ out, int coop, int phase)
{
  __shared__ float les[2048];                 // logz reduce / init zl (8 KB)
  const int bid = blockIdx.x, t = threadIdx.x;
  const int lane = t & 63, wv = t >> 6;
  const int c16 = lane & 15, q = lane >> 4;

  // ================= PHASE 1: tables + init =================
  if (phase & 1){
    if (bid < 192){
      const int sg = bid / 24, tile = bid % 24;
      half8 afr[4][4];
      #pragma unroll
      for (int rt = 0; rt < 4; ++rt){
        const float* mp = move + (sg*64 + rt*16 + c16)*D_ + q*8;
        #pragma unroll
        for (int kk = 0; kk < 4; ++kk){
          float4 f0 = *(const float4*)(mp + kk*32);
          float4 f1 = *(const float4*)(mp + kk*32 + 4);
          half8 a;
          a[0]=(_Float16)f0.x; a[1]=(_Float16)f0.y; a[2]=(_Float16)f0.z; a[3]=(_Float16)f0.w;
          a[4]=(_Float16)f1.x; a[5]=(_Float16)f1.y; a[6]=(_Float16)f1.z; a[7]=(_Float16)f1.w;
          afr[rt][kk] = a;
        }
      }
      const int ct = tile*64 + wv*16 + c16;   // 64-tiles never straddle 512-bounds
      const float* bp; unsigned short* base; int ccol;
      if (ct < 512)      { bp = prefW + ct*256 + 128; base = Hh; ccol = ct; }
      else if (ct < 1024){ bp = prefW + (ct-512)*256; base = Lh; ccol = ct-512; }
      else               { bp = move + (ct-1024)*128; base = Gh; ccol = ct-1024; }
      half8 bfr[4];
      #pragma unroll
      for (int kk = 0; kk < 4; ++kk){
        float4 f0 = *(const float4*)(bp + q*8 + kk*32);
        float4 f1 = *(const float4*)(bp + q*8 + kk*32 + 4);
        half8 bb;
        bb[0]=(_Float16)f0.x; bb[1]=(_Float16)f0.y; bb[2]=(_Float16)f0.z; bb[3]=(_Float16)f0.w;
        bb[4]=(_Float16)f1.x; bb[5]=(_Float16)f1.y; bb[6]=(_Float16)f1.z; bb[7]=(_Float16)f1.w;
        bfr[kk] = bb;
      }
      #pragma unroll
      for (int rt = 0; rt < 4; ++rt){
        f32x4 acc = {0.f,0.f,0.f,0.f};
        #pragma unroll
        for (int kk = 0; kk < 4; ++kk)
          acc = __builtin_amdgcn_mfma_f32_16x16x32_f16(afr[rt][kk], bfr[kk], acc, 0, 0, 0);
        #pragma unroll
        for (int r = 0; r < 4; ++r){
          const int w = sg*64 + rt*16 + q*4 + r;
          base[w*ST_ + ccol] = f2h(acc[r]);
        }
      }
    } else if (bid < 208){
      const int b = bid - 192;
      float* zl = les;
      if (t < 128) zl[t] = latent[zi[b]*D_ + t];
      __syncthreads();

      #pragma unroll
      for (int ii = 0; ii < 2; ++ii){
        const int sidx = t + ii*256;
        const float* wr = prefW + sidx*256;
        const float* mv = move + sidx*128;
        float hu = 0.f, lu = 0.f, d0 = 0.f;
        #pragma unroll 8
        for (int j = 0; j < 128; j += 4){
          float4 w0 = *(const float4*)(wr + j);
          float4 w1 = *(const float4*)(wr + 128 + j);
          float4 m  = *(const float4*)(mv + j);
          float4 z  = *(const float4*)(&zl[j]);
          lu += w0.x*z.x + w0.y*z.y + w0.z*z.z + w0.w*z.w;
          hu += w1.x*z.x + w1.y*z.y + w1.z*z.z + w1.w*z.w;
          d0 += m.x*z.x + m.y*z.y + m.z*z.z + m.w*z.w;
        }
        HU0[b*ST_ + sidx] = hu; LU0[b*ST_ + sidx] = lu; D0[b*ST_ + sidx] = d0;
      }
      if (t < 64){
        float a = zl[t], bb = zl[t + 64];
        float s1 = a + bb, s2 = a*a + bb*bb;
        #pragma unroll
        for (int m = 1; m < 64; m <<= 1){ s1 += __shfl_xor(s1, m, 64); s2 += __shfl_xor(s2, m, 64); }
        if (t == 0) S0[b] = make_float2(s1, s2);
      }
      { // SM + mbf: row = b*32 + (t>>3), 8 threads/row, 16 cols each
        const int w = b*32 + (t >> 3);
        const float* mw = move + w*128 + (t & 7)*16;
        float4 m0 = *(const float4*)(mw),   m1 = *(const float4*)(mw+4);
        float4 m2 = *(const float4*)(mw+8), m3 = *(const float4*)(mw+12);
        float s1 = m0.x+m0.y+m0.z+m0.w + m1.x+m1.y+m1.z+m1.w
                 + m2.x+m2.y+m2.z+m2.w + m3.x+m3.y+m3.z+m3.w;
        float s2 = m0.x*m0.x+m0.y*m0.y+m0.z*m0.z+m0.w*m0.w
                 + m1.x*m1.x+m1.y*m1.y+m1.z*m1.z+m1.w*m1.w
                 + m2.x*m2.x+m2.y*m2.y+m2.z*m2.z+m2.w*m2.w
                 + m3.x*m3.x+m3.y*m3.y+m3.z*m3.z+m3.w*m3.w;
        #pragma unroll
        for (int m = 1; m < 8; m <<= 1){ s1 += __shfl_xor(s1, m, 64); s2 += __shfl_xor(s2, m, 64); }
        if ((t & 7) == 0) SM[w] = make_float2(s1, s2);
        unsigned* dst = mbf + w*64 + (t & 7)*8;
        dst[0] = packbf(m0.x,m0.y); dst[1] = packbf(m0.z,m0.w);
        dst[2] = packbf(m1.x,m1.y); dst[3] = packbf(m1.z,m1.w);
        dst[4] = packbf(m2.x,m2.y); dst[5] = packbf(m2.z,m2.w);
        dst[6] = packbf(m3.x,m3.y); dst[7] = packbf(m3.z,m3.w);
      }
      if (t < 32) partial[b*32 + t] = 0.f;
    }
  }

  if (coop){ __threadfence(); cg::this_grid().sync(); }

  // ================= PHASE 2: scan (0..159) || logz (160..255) =============
  if (phase & 2){
    if (bid < NCHAIN){
      if (t < 64){
        const int c = bid, b = c / NS_;
        const int l = t, t0 = l*8;

        float HU[8], LU[8], D[8], prev1[8], bias[8];
        #pragma unroll
        for (int k = 0; k < 8; k += 4){
          float4 h = *(const float4*)(HU0 + b*ST_ + t0 + k);
          float4 u = *(const float4*)(LU0 + b*ST_ + t0 + k);
          float4 d = *(const float4*)(D0  + b*ST_ + t0 + k);
          float4 bb= *(const float4*)(prefB + t0 + k);
          HU[k]=h.x; HU[k+1]=h.y; HU[k+2]=h.z; HU[k+3]=h.w;
          LU[k]=u.x; LU[k+1]=u.y; LU[k+2]=u.z; LU[k+3]=u.w;
          D[k]=d.x;  D[k+1]=d.y;  D[k+2]=d.z;  D[k+3]=d.w;
          bias[k]=bb.x; bias[k+1]=bb.y; bias[k+2]=bb.z; bias[k+3]=bb.w;
        }
        #pragma unroll
        for (int k = 0; k < 8; ++k) prev1[k] = 0.f;
        float2 s0 = S0[b];
        float S1 = s0.x, S2 = s0.y;
        float rdreg = (l < T_) ? rd[l*(B_*NS_) + c] : 0.f;

        for (int st = 0; st < T_; ++st){
          const float mean = S1 * (1.f/128.f);
          const float var  = (S2 - 128.f*mean*mean) * (1.f/127.f);
          const float sc   = 0.113f / (1e-5f + sqrtf(var));

          float cum[8]; float run = 0.f;
          #pragma unroll
          for (int k = 0; k < 8; ++k){
            float pref = fmaf(sc, HU[k], prev1[k] + bias[k]);
            run += __expf(pref);
            cum[k] = run;
          }
          float incl = run;
          DPPADD(incl, 0x111, 0xf)
          DPPADD(incl, 0x112, 0xf)
          DPPADD(incl, 0x114, 0xf)
          DPPADD(incl, 0x118, 0xf)
          DPPADD(incl, 0x142, 0xa)
          DPPADD(incl, 0x143, 0xc)
          const float total  = readlane_f(incl, 63);
          const float target = readlane_f(rdreg, st) * total;

          const bool cond = target < incl;
          const unsigned long long bal = __ballot(cond);
          const float excl = incl - run;
          int kw = 7; float dcand = D[7];
          #pragma unroll
          for (int k = 6; k >= 0; --k){
            bool ck = target < excl + cum[k];
            kw = ck ? k : kw;
            dcand = ck ? D[k] : dcand;
          }
          int which; float dW;
          if (bal){
            const int wlane = __ffsll(bal) - 1;
            which = __builtin_amdgcn_readlane(t0 + kw, wlane);
            dW    = readlane_f(dcand, wlane);
          } else {
            which = 0;
            dW    = readlane_f(D[0], 0);
          }
          if (l == 0) whichOut[c*T_ + st] = which;

          const int rb = which*ST_ + t0;
          const uint4 hq = *(const uint4*)(Hh + rb);
          const uint4 lq = *(const uint4*)(Lh + rb);
          const uint4 gq = *(const uint4*)(Gh + rb);
          const float2 sm = SM[which];
          const unsigned ha[4] = {hq.x, hq.y, hq.z, hq.w};
          const unsigned la[4] = {lq.x, lq.y, lq.z, lq.w};
          const unsigned ga[4] = {gq.x, gq.y, gq.z, gq.w};
          #pragma unroll
          for (int k = 0; k < 8; ++k){
            const float Hk = h2f(ha[k>>1], k&1);
            const float Lk = h2f(la[k>>1], k&1);
            const float Gk = h2f(ga[k>>1], k&1);
            const float p1 = sc * LU[k];
            HU[k] = fmaf(sc, HU[k], Hk);
            LU[k] = p1 + Lk;
            D[k]  = fmaf(sc, D[k], Gk);
            prev1[k] = p1;
          }
          S1 = fmaf(sc, S1, sm.x);
          S2 = fmaf(sc*sc, S2, fmaf(2.f*sc, dW, sm.y));
        }
      }
    } else {
      const char* mb = (const char*)mbf;
      for (int u = bid - NCHAIN; u < 250; u += NBLK - NCHAIN){
        const int vbase = u*128 + wv*32;
        short8 afr[2][4];
        float vbr[2][4];
        #pragma unroll
        for (int vt = 0; vt < 2; ++vt){
          const int vr = vbase + vt*16 + c16;
          const float* wp = vw + vr*D_ + q*8;
          #pragma unroll
          for (int kk = 0; kk < 4; ++kk){
            float4 f0 = *(const float4*)(wp + kk*32);
            float4 f1 = *(const float4*)(wp + kk*32 + 4);
            short8 a;
            a[0]=(short)f2bf(f0.x); a[1]=(short)f2bf(f0.y);
            a[2]=(short)f2bf(f0.z); a[3]=(short)f2bf(f0.w);
            a[4]=(short)f2bf(f1.x); a[5]=(short)f2bf(f1.y);
            a[6]=(short)f2bf(f1.z); a[7]=(short)f2bf(f1.w);
            afr[vt][kk] = a;
          }
          #pragma unroll
          for (int r = 0; r < 4; ++r)
            vbr[vt][r] = vb[vbase + vt*16 + q*4 + r];
        }

        float esl[32];
        #pragma unroll
        for (int s = 0; s < 32; ++s) esl[s] = 0.f;

        #pragma unroll
        for (int s = 0; s < 32; ++s){
          short8 bfr[4];
          #pragma unroll
          for (int kk = 0; kk < 4; ++kk){
            const int row = s*16 + c16;
            bfr[kk] = *(const short8*)(mb + row*256 + q*16 + kk*64);
          }
          #pragma unroll
          for (int vt = 0; vt < 2; ++vt){
            f32x4 acc = {0.f,0.f,0.f,0.f};
            #pragma unroll
            for (int kk = 0; kk < 4; ++kk)
              acc = __builtin_amdgcn_mfma_f32_16x16x32_bf16(afr[vt][kk], bfr[kk], acc, 0, 0, 0);
            #pragma unroll
            for (int r = 0; r < 4; ++r)
              esl[s] += __expf(acc[r] + vbr[vt][r]);
          }
        }
        #pragma unroll
        for (int s = 0; s < 32; ++s){
          esl[s] += __shfl_xor(esl[s], 16, 64);
          esl[s] += __shfl_xor(esl[s], 32, 64);
        }
        if (lane < 16){
          #pragma unroll
          for (int s = 0; s < 32; ++s) les[wv*512 + s*16 + lane] = esl[s];
        }
        __syncthreads();
        #pragma unroll
        for (int i = 0; i < 2; ++i){
          const int st = t + i*256;
          atomicAdd(&partial[st], les[st] + les[512+st] + les[1024+st] + les[1536+st]);
        }
        __syncthreads();     // les reused next tile
      }
    }
  }

  if (coop){ __threadfence(); cg::this_grid().sync(); }

  // ================= PHASE 3: dots =================
  if (phase & 4){
    if (bid < 128){
      const int p = bid*4 + wv;            // 0..511
      const int b = p >> 5, st = p & 31;

      int w10 = 0; float ls = 0.f;
      if (lane < NS_){
        w10 = whichOut[(b*NS_ + lane)*T_ + st];
        ls  = __logf(partial[w10]);
      }
      #pragma unroll
      for (int m = 1; m < 16; m <<= 1) ls += __shfl_xor(ls, m, 64);

      float mv0 = 0.f, mv1 = 0.f;
      #pragma unroll
      for (int s = 0; s < NS_; ++s){
        const int ws = __builtin_amdgcn_readlane(w10, s);
        mv0 += move[ws*D_ + lane];
        mv1 += move[ws*D_ + 64 + lane];
      }
      const int yr = y[b*T_ + st];
      float pacc = mv0*vw[yr*D_ + lane] + mv1*vw[yr*D_ + 64 + lane];
      #pragma unroll
      for (int m = 1; m < 64; m <<= 1) pacc += __shfl_xor(pacc, m, 64);
      if (lane == 0) out[b*T_ + st] = (pacc - ls) * (1.f/NS_) + vb[yr];
    }
  }
}

extern "C" void kernel_launch(void* const* d_in, const int* in_sizes, int n_in,
                              void* d_out, int out_size, void* d_ws, size_t ws_size,
                              hipStream_t stream)
{
  const int*   zi     = (const int*)d_in[0];
  const int*   y      = (const int*)d_in[1];
  const float* rd     = (const float*)d_in[2];
  const float* latent = (const float*)d_in[3];
  const float* prefW  = (const float*)d_in[4];
  const float* prefB  = (const float*)d_in[5];
  const float* move   = (const float*)d_in[6];
  const float* vw     = (const float*)d_in[7];
  const float* vb     = (const float*)d_in[8];
  float* out = (float*)d_out;

  char* ws = (char*)d_ws;
  unsigned short* Hh = (unsigned short*)(ws);           // 512 KB
  unsigned short* Lh = (unsigned short*)(ws + 524288);  // 512 KB
  unsigned short* Gh = (unsigned short*)(ws + 1048576); // 512 KB
  float2* SM    = (float2*)(ws + 1572864);              // 4 KB
  float*  HU0   = (float*)(ws + 1576960);               // 32 KB
  float*  LU0   = (float*)(ws + 1609728);               // 32 KB
  float*  D0    = (float*)(ws + 1642496);               // 32 KB
  float2* S0    = (float2*)(ws + 1675264);              // 128 B
  float*  partial = (float*)(ws + 1675392);             // 2 KB
  int*    which = (int*)(ws + 1677440);                 // 20 KB
  unsigned* mbf = (unsigned*)(ws + 1697920);            // 128 KB (bf16 move)

  int coop1 = 1, phase7 = 7;
  void* args[] = {
    (void*)&zi, (void*)&y, (void*)&rd, (void*)&latent, (void*)&prefW,
    (void*)&prefB, (void*)&move, (void*)&vw, (void*)&vb,
    (void*)&Hh, (void*)&Lh, (void*)&Gh, (void*)&SM,
    (void*)&HU0, (void*)&LU0, (void*)&D0, (void*)&S0,
    (void*)&partial, (void*)&which, (void*)&mbf, (void*)&out,
    (void*)&coop1, (void*)&phase7
  };
  hipError_t e = hipLaunchCooperativeKernel((const void*)fused_kernel,
                                            dim3(NBLK), dim3(256), args, 0, stream);
  if (e != hipSuccess){
    (void)hipGetLastError();   // clear sticky error; fall back to 3 sequential launches
    hipLaunchKernelGGL(fused_kernel, dim3(NBLK), dim3(256), 0, stream,
                       zi, y, rd, latent, prefW, prefB, move, vw, vb,
                       Hh, Lh, Gh, SM, HU0, LU0, D0, S0, partial, which, mbf,
                       out, 0, 1);
    hipLaunchKernelGGL(fused_kernel, dim3(NBLK), dim3(256), 0, stream,
                       zi, y, rd, latent, prefW, prefB, move, vw, vb,
                       Hh, Lh, Gh, SM, HU0, LU0, D0, S0, partial, which, mbf,
                       out, 0, 2);
    hipLaunchKernelGGL(fused_kernel, dim3(NBLK), dim3(256), 0, stream,
                       zi, y, rd, latent, prefW, prefB, move, vw, vb,
                       Hh, Lh, Gh, SM, HU0, LU0, D0, S0, partial, which, mbf,
                       out, 0, 4);
  }
}

// Round 10
// 168.010 us; speedup vs baseline: 1.3046x; 1.3046x over previous
//
#include <hip/hip_runtime.h>
#include <hip/hip_bf16.h>

#define B_ 16
#define T_ 32
#define NS_ 10
#define D_ 128
#define ST_ 512
#define V_ 32000
#define NCHAIN 160
#define NBLK2 256         // node-2 grid: <= CU count, all blocks resident

using short8  = __attribute__((ext_vector_type(8))) short;
using f32x4   = __attribute__((ext_vector_type(4))) float;
using half8   = __attribute__((ext_vector_type(8))) _Float16;
using half2v  = __attribute__((ext_vector_type(2))) _Float16;

__device__ __forceinline__ unsigned short f2bf(float f){
  unsigned u = __float_as_uint(f);
  u += 0x7FFFu + ((u >> 16) & 1u);          // RNE to bf16
  return (unsigned short)(u >> 16);
}
__device__ __forceinline__ unsigned packbf(float a, float b){
  return ((unsigned)f2bf(b) << 16) | (unsigned)f2bf(a);
}
__device__ __forceinline__ unsigned short f2h(float f){
  return __builtin_bit_cast(unsigned short, (_Float16)f);
}
__device__ __forceinline__ float h2f(unsigned u, int hi){
  half2v h = __builtin_bit_cast(half2v, u);
  return (float)h[hi];
}
__device__ __forceinline__ float readlane_f(float v, int lane){
  return __int_as_float(__builtin_amdgcn_readlane(__float_as_int(v), lane));
}

// wave64 inclusive scan via DPP: 6 ops
#define DPPADD(x, ctrl, rm) { \
  int _t = __builtin_amdgcn_update_dpp(0, __float_as_int(x), ctrl, rm, 0xf, true); \
  x += __int_as_float(_t); }

// ---------------------------------------------------------------------------
// Node 1: prep. 208 blocks x 256 thr.
//  blocks 0..191 : tables  C[w][ct] = move_w . Brow(ct) (f16 MFMA -> Hh/Lh/Gh)
//  blocks 192..207: per-batch init + SM + mbf + zero partial + zero barrier
// ---------------------------------------------------------------------------
__global__ __launch_bounds__(256) void prep_kernel(
    const int* __restrict__ zi, const float* __restrict__ latent,
    const float* __restrict__ prefW, const float* __restrict__ move,
    unsigned short* __restrict__ Hh, unsigned short* __restrict__ Lh,
    unsigned short* __restrict__ Gh,
    float* __restrict__ HU0, float* __restrict__ LU0, float* __restrict__ D0,
    float2* __restrict__ S0, float2* __restrict__ SM,
    unsigned* __restrict__ mbf, float* __restrict__ partial,
    int* __restrict__ bar)
{
  const int bid = blockIdx.x, t = threadIdx.x;
  const int lane = t & 63, wv = t >> 6;
  const int c16 = lane & 15, q = lane >> 4;

  if (bid < 192){
    const int sg = bid / 24, tile = bid % 24;
    half8 afr[4][4];
    #pragma unroll
    for (int rt = 0; rt < 4; ++rt){
      const float* mp = move + (sg*64 + rt*16 + c16)*D_ + q*8;
      #pragma unroll
      for (int kk = 0; kk < 4; ++kk){
        float4 f0 = *(const float4*)(mp + kk*32);
        float4 f1 = *(const float4*)(mp + kk*32 + 4);
        half8 a;
        a[0]=(_Float16)f0.x; a[1]=(_Float16)f0.y; a[2]=(_Float16)f0.z; a[3]=(_Float16)f0.w;
        a[4]=(_Float16)f1.x; a[5]=(_Float16)f1.y; a[6]=(_Float16)f1.z; a[7]=(_Float16)f1.w;
        afr[rt][kk] = a;
      }
    }
    const int ct = tile*64 + wv*16 + c16;     // 64-tiles never straddle 512-bounds
    const float* bp; unsigned short* base; int ccol;
    if (ct < 512)      { bp = prefW + ct*256 + 128; base = Hh; ccol = ct; }
    else if (ct < 1024){ bp = prefW + (ct-512)*256; base = Lh; ccol = ct-512; }
    else               { bp = move + (ct-1024)*128; base = Gh; ccol = ct-1024; }
    half8 bfr[4];
    #pragma unroll
    for (int kk = 0; kk < 4; ++kk){
      float4 f0 = *(const float4*)(bp + q*8 + kk*32);
      float4 f1 = *(const float4*)(bp + q*8 + kk*32 + 4);
      half8 bb;
      bb[0]=(_Float16)f0.x; bb[1]=(_Float16)f0.y; bb[2]=(_Float16)f0.z; bb[3]=(_Float16)f0.w;
      bb[4]=(_Float16)f1.x; bb[5]=(_Float16)f1.y; bb[6]=(_Float16)f1.z; bb[7]=(_Float16)f1.w;
      bfr[kk] = bb;
    }
    #pragma unroll
    for (int rt = 0; rt < 4; ++rt){
      f32x4 acc = {0.f,0.f,0.f,0.f};
      #pragma unroll
      for (int kk = 0; kk < 4; ++kk)
        acc = __builtin_amdgcn_mfma_f32_16x16x32_f16(afr[rt][kk], bfr[kk], acc, 0, 0, 0);
      #pragma unroll
      for (int r = 0; r < 4; ++r){
        const int w = sg*64 + rt*16 + q*4 + r;
        base[w*ST_ + ccol] = f2h(acc[r]);
      }
    }
  } else {
    const int b = bid - 192;
    __shared__ float zl[128];
    if (t < 128) zl[t] = latent[zi[b]*D_ + t];
    __syncthreads();

    #pragma unroll
    for (int ii = 0; ii < 2; ++ii){
      const int sidx = t + ii*256;
      const float* wr = prefW + sidx*256;
      const float* mv = move + sidx*128;
      float hu = 0.f, lu = 0.f, d0 = 0.f;
      #pragma unroll 8
      for (int j = 0; j < 128; j += 4){
        float4 w0 = *(const float4*)(wr + j);
        float4 w1 = *(const float4*)(wr + 128 + j);
        float4 m  = *(const float4*)(mv + j);
        float4 z  = *(const float4*)(&zl[j]);
        lu += w0.x*z.x + w0.y*z.y + w0.z*z.z + w0.w*z.w;
        hu += w1.x*z.x + w1.y*z.y + w1.z*z.z + w1.w*z.w;
        d0 += m.x*z.x + m.y*z.y + m.z*z.z + m.w*z.w;
      }
      HU0[b*ST_ + sidx] = hu; LU0[b*ST_ + sidx] = lu; D0[b*ST_ + sidx] = d0;
    }
    if (t < 64){
      float a = zl[t], bb = zl[t + 64];
      float s1 = a + bb, s2 = a*a + bb*bb;
      #pragma unroll
      for (int m = 1; m < 64; m <<= 1){ s1 += __shfl_xor(s1, m, 64); s2 += __shfl_xor(s2, m, 64); }
      if (t == 0) S0[b] = make_float2(s1, s2);
    }
    { // SM + mbf: row = b*32 + (t>>3), 8 threads/row, 16 cols each
      const int w = b*32 + (t >> 3);
      const float* mw = move + w*128 + (t & 7)*16;
      float4 m0 = *(const float4*)(mw),   m1 = *(const float4*)(mw+4);
      float4 m2 = *(const float4*)(mw+8), m3 = *(const float4*)(mw+12);
      float s1 = m0.x+m0.y+m0.z+m0.w + m1.x+m1.y+m1.z+m1.w
               + m2.x+m2.y+m2.z+m2.w + m3.x+m3.y+m3.z+m3.w;
      float s2 = m0.x*m0.x+m0.y*m0.y+m0.z*m0.z+m0.w*m0.w
               + m1.x*m1.x+m1.y*m1.y+m1.z*m1.z+m1.w*m1.w
               + m2.x*m2.x+m2.y*m2.y+m2.z*m2.z+m2.w*m2.w
               + m3.x*m3.x+m3.y*m3.y+m3.z*m3.z+m3.w*m3.w;
      #pragma unroll
      for (int m = 1; m < 8; m <<= 1){ s1 += __shfl_xor(s1, m, 64); s2 += __shfl_xor(s2, m, 64); }
      if ((t & 7) == 0) SM[w] = make_float2(s1, s2);
      unsigned* dst = mbf + w*64 + (t & 7)*8;
      dst[0] = packbf(m0.x,m0.y); dst[1] = packbf(m0.z,m0.w);
      dst[2] = packbf(m1.x,m1.y); dst[3] = packbf(m1.z,m1.w);
      dst[4] = packbf(m2.x,m2.y); dst[5] = packbf(m2.z,m2.w);
      dst[6] = packbf(m3.x,m3.y); dst[7] = packbf(m3.z,m3.w);
    }
    if (t < 32) partial[b*32 + t] = 0.f;
    if (b == 0 && t == 64) *bar = 0;      // reset barrier each replay (stream-ordered)
  }
}

// ---------------------------------------------------------------------------
// Node 2: scan (blocks 0..159) || logz (160..255, grid-stride 250 tiles)
//         -> hand-rolled resident-grid barrier -> dots (blocks 0..127).
// ---------------------------------------------------------------------------
__global__ __launch_bounds__(256) void workdots_kernel(
    const unsigned short* __restrict__ Hh, const unsigned short* __restrict__ Lh,
    const unsigned short* __restrict__ Gh, const float2* __restrict__ SM,
    const float* __restrict__ HU0, const float* __restrict__ LU0,
    const float* __restrict__ D0, const float2* __restrict__ S0,
    const float* __restrict__ prefB, const float* __restrict__ rd,
    int* __restrict__ whichOut,
    const unsigned* __restrict__ mbf, const float* __restrict__ vw,
    const float* __restrict__ vb, float* __restrict__ partial,
    const int* __restrict__ y, const float* __restrict__ move,
    float* __restrict__ out, int* __restrict__ bar)
{
  __shared__ float les[2048];               // logz reduce (8 KB)
  const int bid = blockIdx.x, t = threadIdx.x;
  const int lane = t & 63, wv = t >> 6;
  const int c16 = lane & 15, q = lane >> 4;

  // ================= phase A: scan || logz =================
  if (bid < NCHAIN){
    if (t < 64){
      const int c = bid, b = c / NS_;
      const int l = t, t0 = l*8;

      float HU[8], LU[8], D[8], prev1[8], bias[8];
      #pragma unroll
      for (int k = 0; k < 8; k += 4){
        float4 h = *(const float4*)(HU0 + b*ST_ + t0 + k);
        float4 u = *(const float4*)(LU0 + b*ST_ + t0 + k);
        float4 d = *(const float4*)(D0  + b*ST_ + t0 + k);
        float4 bb= *(const float4*)(prefB + t0 + k);
        HU[k]=h.x; HU[k+1]=h.y; HU[k+2]=h.z; HU[k+3]=h.w;
        LU[k]=u.x; LU[k+1]=u.y; LU[k+2]=u.z; LU[k+3]=u.w;
        D[k]=d.x;  D[k+1]=d.y;  D[k+2]=d.z;  D[k+3]=d.w;
        bias[k]=bb.x; bias[k+1]=bb.y; bias[k+2]=bb.z; bias[k+3]=bb.w;
      }
      #pragma unroll
      for (int k = 0; k < 8; ++k) prev1[k] = 0.f;
      float2 s0 = S0[b];
      float S1 = s0.x, S2 = s0.y;
      float rdreg = (l < T_) ? rd[l*(B_*NS_) + c] : 0.f;

      for (int st = 0; st < T_; ++st){
        const float mean = S1 * (1.f/128.f);
        const float var  = (S2 - 128.f*mean*mean) * (1.f/127.f);
        const float sc   = 0.113f / (1e-5f + sqrtf(var));

        float cum[8]; float run = 0.f;
        #pragma unroll
        for (int k = 0; k < 8; ++k){
          float pref = fmaf(sc, HU[k], prev1[k] + bias[k]);
          run += __expf(pref);
          cum[k] = run;
        }
        float incl = run;
        DPPADD(incl, 0x111, 0xf)
        DPPADD(incl, 0x112, 0xf)
        DPPADD(incl, 0x114, 0xf)
        DPPADD(incl, 0x118, 0xf)
        DPPADD(incl, 0x142, 0xa)
        DPPADD(incl, 0x143, 0xc)
        const float total  = readlane_f(incl, 63);
        const float target = readlane_f(rdreg, st) * total;

        const bool cond = target < incl;
        const unsigned long long bal = __ballot(cond);
        const float excl = incl - run;
        int kw = 7; float dcand = D[7];
        #pragma unroll
        for (int k = 6; k >= 0; --k){
          bool ck = target < excl + cum[k];
          kw = ck ? k : kw;
          dcand = ck ? D[k] : dcand;
        }
        int which; float dW;
        if (bal){
          const int wlane = __ffsll(bal) - 1;
          which = __builtin_amdgcn_readlane(t0 + kw, wlane);
          dW    = readlane_f(dcand, wlane);
        } else {
          which = 0;
          dW    = readlane_f(D[0], 0);
        }
        if (l == 0) whichOut[c*T_ + st] = which;

        const int rb = which*ST_ + t0;
        const uint4 hq = *(const uint4*)(Hh + rb);
        const uint4 lq = *(const uint4*)(Lh + rb);
        const uint4 gq = *(const uint4*)(Gh + rb);
        const float2 sm = SM[which];
        const unsigned ha[4] = {hq.x, hq.y, hq.z, hq.w};
        const unsigned la[4] = {lq.x, lq.y, lq.z, lq.w};
        const unsigned ga[4] = {gq.x, gq.y, gq.z, gq.w};
        #pragma unroll
        for (int k = 0; k < 8; ++k){
          const float Hk = h2f(ha[k>>1], k&1);
          const float Lk = h2f(la[k>>1], k&1);
          const float Gk = h2f(ga[k>>1], k&1);
          const float p1 = sc * LU[k];
          HU[k] = fmaf(sc, HU[k], Hk);
          LU[k] = p1 + Lk;
          D[k]  = fmaf(sc, D[k], Gk);
          prev1[k] = p1;
        }
        S1 = fmaf(sc, S1, sm.x);
        S2 = fmaf(sc*sc, S2, fmaf(2.f*sc, dW, sm.y));
      }
    }
  } else {
    const char* mb = (const char*)mbf;
    for (int u = bid - NCHAIN; u < 250; u += NBLK2 - NCHAIN){
      const int vbase = u*128 + wv*32;
      short8 afr[2][4];
      float vbr[2][4];
      #pragma unroll
      for (int vt = 0; vt < 2; ++vt){
        const int vr = vbase + vt*16 + c16;
        const float* wp = vw + vr*D_ + q*8;
        #pragma unroll
        for (int kk = 0; kk < 4; ++kk){
          float4 f0 = *(const float4*)(wp + kk*32);
          float4 f1 = *(const float4*)(wp + kk*32 + 4);
          short8 a;
          a[0]=(short)f2bf(f0.x); a[1]=(short)f2bf(f0.y);
          a[2]=(short)f2bf(f0.z); a[3]=(short)f2bf(f0.w);
          a[4]=(short)f2bf(f1.x); a[5]=(short)f2bf(f1.y);
          a[6]=(short)f2bf(f1.z); a[7]=(short)f2bf(f1.w);
          afr[vt][kk] = a;
        }
        #pragma unroll
        for (int r = 0; r < 4; ++r)
          vbr[vt][r] = vb[vbase + vt*16 + q*4 + r];
      }

      float esl[32];
      #pragma unroll
      for (int s = 0; s < 32; ++s) esl[s] = 0.f;

      #pragma unroll
      for (int s = 0; s < 32; ++s){
        short8 bfr[4];
        #pragma unroll
        for (int kk = 0; kk < 4; ++kk){
          const int row = s*16 + c16;
          bfr[kk] = *(const short8*)(mb + row*256 + q*16 + kk*64);
        }
        #pragma unroll
        for (int vt = 0; vt < 2; ++vt){
          f32x4 acc = {0.f,0.f,0.f,0.f};
          #pragma unroll
          for (int kk = 0; kk < 4; ++kk)
            acc = __builtin_amdgcn_mfma_f32_16x16x32_bf16(afr[vt][kk], bfr[kk], acc, 0, 0, 0);
          #pragma unroll
          for (int r = 0; r < 4; ++r)
            esl[s] += __expf(acc[r] + vbr[vt][r]);
        }
      }
      #pragma unroll
      for (int s = 0; s < 32; ++s){
        esl[s] += __shfl_xor(esl[s], 16, 64);
        esl[s] += __shfl_xor(esl[s], 32, 64);
      }
      if (lane < 16){
        #pragma unroll
        for (int s = 0; s < 32; ++s) les[wv*512 + s*16 + lane] = esl[s];
      }
      __syncthreads();
      #pragma unroll
      for (int i = 0; i < 2; ++i){
        const int st = t + i*256;
        atomicAdd(&partial[st], les[st] + les[512+st] + les[1024+st] + les[1536+st]);
      }
      __syncthreads();     // les reused next tile
    }
  }

  // ================= resident-grid barrier =================
  __syncthreads();
  if (t == 0){
    __threadfence();                                   // release our stores
    __hip_atomic_fetch_add(bar, 1, __ATOMIC_ACQ_REL, __HIP_MEMORY_SCOPE_AGENT);
    while (__hip_atomic_load(bar, __ATOMIC_ACQUIRE, __HIP_MEMORY_SCOPE_AGENT) < NBLK2)
      __builtin_amdgcn_s_sleep(2);
  }
  __syncthreads();
  __threadfence();                                     // acquire others' stores

  // ================= phase B: dots =================
  if (bid < 128){
    const int p = bid*4 + wv;            // 0..511
    const int b = p >> 5, st = p & 31;

    int w10 = 0; float ls = 0.f;
    if (lane < NS_){
      w10 = whichOut[(b*NS_ + lane)*T_ + st];
      ls  = __logf(partial[w10]);
    }
    #pragma unroll
    for (int m = 1; m < 16; m <<= 1) ls += __shfl_xor(ls, m, 64);

    float mv0 = 0.f, mv1 = 0.f;
    #pragma unroll
    for (int s = 0; s < NS_; ++s){
      const int ws = __builtin_amdgcn_readlane(w10, s);
      mv0 += move[ws*D_ + lane];
      mv1 += move[ws*D_ + 64 + lane];
    }
    const int yr = y[b*T_ + st];
    float pacc = mv0*vw[yr*D_ + lane] + mv1*vw[yr*D_ + 64 + lane];
    #pragma unroll
    for (int m = 1; m < 64; m <<= 1) pacc += __shfl_xor(pacc, m, 64);
    if (lane == 0) out[b*T_ + st] = (pacc - ls) * (1.f/NS_) + vb[yr];
  }
}

extern "C" void kernel_launch(void* const* d_in, const int* in_sizes, int n_in,
                              void* d_out, int out_size, void* d_ws, size_t ws_size,
                              hipStream_t stream)
{
  const int*   zi     = (const int*)d_in[0];
  const int*   y      = (const int*)d_in[1];
  const float* rd     = (const float*)d_in[2];
  const float* latent = (const float*)d_in[3];
  const float* prefW  = (const float*)d_in[4];
  const float* prefB  = (const float*)d_in[5];
  const float* move   = (const float*)d_in[6];
  const float* vw     = (const float*)d_in[7];
  const float* vb     = (const float*)d_in[8];
  float* out = (float*)d_out;

  char* ws = (char*)d_ws;
  unsigned short* Hh = (unsigned short*)(ws);           // 512 KB
  unsigned short* Lh = (unsigned short*)(ws + 524288);  // 512 KB
  unsigned short* Gh = (unsigned short*)(ws + 1048576); // 512 KB
  float2* SM    = (float2*)(ws + 1572864);              // 4 KB
  float*  HU0   = (float*)(ws + 1576960);               // 32 KB
  float*  LU0   = (float*)(ws + 1609728);               // 32 KB
  float*  D0    = (float*)(ws + 1642496);               // 32 KB
  float2* S0    = (float2*)(ws + 1675264);              // 128 B
  float*  partial = (float*)(ws + 1675392);             // 2 KB
  int*    which = (int*)(ws + 1677440);                 // 20 KB
  unsigned* mbf = (unsigned*)(ws + 1697920);            // 128 KB (bf16 move)
  int*    bar   = (int*)(ws + 1828992);                 // 4 B barrier counter

  hipLaunchKernelGGL(prep_kernel, dim3(208), dim3(256), 0, stream,
                     zi, latent, prefW, move, Hh, Lh, Gh,
                     HU0, LU0, D0, S0, SM, mbf, partial, bar);
  hipLaunchKernelGGL(workdots_kernel, dim3(NBLK2), dim3(256), 0, stream,
                     Hh, Lh, Gh, SM, HU0, LU0, D0, S0, prefB, rd, which,
                     mbf, vw, vb, partial, y, move, out, bar);
}

// Round 11
// 102.179 us; speedup vs baseline: 2.1450x; 1.6443x over previous
//
#include <hip/hip_runtime.h>
#include <hip/hip_bf16.h>

#define B_ 16
#define T_ 32
#define NS_ 10
#define D_ 128
#define ST_ 512
#define V_ 32000
#define NCHAIN 160
#define NBLK2 256         // node-2 grid
#define NLOGZ (NBLK2 - NCHAIN)   // 96 logz blocks

using short8  = __attribute__((ext_vector_type(8))) short;
using f32x4   = __attribute__((ext_vector_type(4))) float;
using half8   = __attribute__((ext_vector_type(8))) _Float16;
using half2v  = __attribute__((ext_vector_type(2))) _Float16;

__device__ __forceinline__ unsigned short f2bf(float f){
  unsigned u = __float_as_uint(f);
  u += 0x7FFFu + ((u >> 16) & 1u);          // RNE to bf16
  return (unsigned short)(u >> 16);
}
__device__ __forceinline__ unsigned packbf(float a, float b){
  return ((unsigned)f2bf(b) << 16) | (unsigned)f2bf(a);
}
__device__ __forceinline__ unsigned short f2h(float f){
  return __builtin_bit_cast(unsigned short, (_Float16)f);
}
__device__ __forceinline__ float h2f(unsigned u, int hi){
  half2v h = __builtin_bit_cast(half2v, u);
  return (float)h[hi];
}
__device__ __forceinline__ float readlane_f(float v, int lane){
  return __int_as_float(__builtin_amdgcn_readlane(__float_as_int(v), lane));
}

// wave64 inclusive scan via DPP: 6 ops
#define DPPADD(x, ctrl, rm) { \
  int _t = __builtin_amdgcn_update_dpp(0, __float_as_int(x), ctrl, rm, 0xf, true); \
  x += __int_as_float(_t); }

// ---------------------------------------------------------------------------
// Node 1: prep. 208 blocks x 256 thr.
//  blocks 0..191 : tables  C[w][ct] = move_w . Brow(ct) (f16 MFMA -> Hh/Lh/Gh)
//  blocks 192..207: per-batch init + SM + mbf + zero partial/out/logzdone
// ---------------------------------------------------------------------------
__global__ __launch_bounds__(256) void prep_kernel(
    const int* __restrict__ zi, const float* __restrict__ latent,
    const float* __restrict__ prefW, const float* __restrict__ move,
    unsigned short* __restrict__ Hh, unsigned short* __restrict__ Lh,
    unsigned short* __restrict__ Gh,
    float* __restrict__ HU0, float* __restrict__ LU0, float* __restrict__ D0,
    float2* __restrict__ S0, float2* __restrict__ SM,
    unsigned* __restrict__ mbf, float* __restrict__ partial,
    float* __restrict__ out, int* __restrict__ logzdone)
{
  const int bid = blockIdx.x, t = threadIdx.x;
  const int lane = t & 63, wv = t >> 6;
  const int c16 = lane & 15, q = lane >> 4;

  if (bid < 192){
    const int sg = bid / 24, tile = bid % 24;
    half8 afr[4][4];
    #pragma unroll
    for (int rt = 0; rt < 4; ++rt){
      const float* mp = move + (sg*64 + rt*16 + c16)*D_ + q*8;
      #pragma unroll
      for (int kk = 0; kk < 4; ++kk){
        float4 f0 = *(const float4*)(mp + kk*32);
        float4 f1 = *(const float4*)(mp + kk*32 + 4);
        half8 a;
        a[0]=(_Float16)f0.x; a[1]=(_Float16)f0.y; a[2]=(_Float16)f0.z; a[3]=(_Float16)f0.w;
        a[4]=(_Float16)f1.x; a[5]=(_Float16)f1.y; a[6]=(_Float16)f1.z; a[7]=(_Float16)f1.w;
        afr[rt][kk] = a;
      }
    }
    const int ct = tile*64 + wv*16 + c16;     // 64-tiles never straddle 512-bounds
    const float* bp; unsigned short* base; int ccol;
    if (ct < 512)      { bp = prefW + ct*256 + 128; base = Hh; ccol = ct; }
    else if (ct < 1024){ bp = prefW + (ct-512)*256; base = Lh; ccol = ct-512; }
    else               { bp = move + (ct-1024)*128; base = Gh; ccol = ct-1024; }
    half8 bfr[4];
    #pragma unroll
    for (int kk = 0; kk < 4; ++kk){
      float4 f0 = *(const float4*)(bp + q*8 + kk*32);
      float4 f1 = *(const float4*)(bp + q*8 + kk*32 + 4);
      half8 bb;
      bb[0]=(_Float16)f0.x; bb[1]=(_Float16)f0.y; bb[2]=(_Float16)f0.z; bb[3]=(_Float16)f0.w;
      bb[4]=(_Float16)f1.x; bb[5]=(_Float16)f1.y; bb[6]=(_Float16)f1.z; bb[7]=(_Float16)f1.w;
      bfr[kk] = bb;
    }
    #pragma unroll
    for (int rt = 0; rt < 4; ++rt){
      f32x4 acc = {0.f,0.f,0.f,0.f};
      #pragma unroll
      for (int kk = 0; kk < 4; ++kk)
        acc = __builtin_amdgcn_mfma_f32_16x16x32_f16(afr[rt][kk], bfr[kk], acc, 0, 0, 0);
      #pragma unroll
      for (int r = 0; r < 4; ++r){
        const int w = sg*64 + rt*16 + q*4 + r;
        base[w*ST_ + ccol] = f2h(acc[r]);
      }
    }
  } else {
    const int b = bid - 192;
    __shared__ float zl[128];
    if (t < 128) zl[t] = latent[zi[b]*D_ + t];
    __syncthreads();

    #pragma unroll
    for (int ii = 0; ii < 2; ++ii){
      const int sidx = t + ii*256;
      const float* wr = prefW + sidx*256;
      const float* mv = move + sidx*128;
      float hu = 0.f, lu = 0.f, d0 = 0.f;
      #pragma unroll 8
      for (int j = 0; j < 128; j += 4){
        float4 w0 = *(const float4*)(wr + j);
        float4 w1 = *(const float4*)(wr + 128 + j);
        float4 m  = *(const float4*)(mv + j);
        float4 z  = *(const float4*)(&zl[j]);
        lu += w0.x*z.x + w0.y*z.y + w0.z*z.z + w0.w*z.w;
        hu += w1.x*z.x + w1.y*z.y + w1.z*z.z + w1.w*z.w;
        d0 += m.x*z.x + m.y*z.y + m.z*z.z + m.w*z.w;
      }
      HU0[b*ST_ + sidx] = hu; LU0[b*ST_ + sidx] = lu; D0[b*ST_ + sidx] = d0;
    }
    if (t < 64){
      float a = zl[t], bb = zl[t + 64];
      float s1 = a + bb, s2 = a*a + bb*bb;
      #pragma unroll
      for (int m = 1; m < 64; m <<= 1){ s1 += __shfl_xor(s1, m, 64); s2 += __shfl_xor(s2, m, 64); }
      if (t == 0) S0[b] = make_float2(s1, s2);
    }
    { // SM + mbf: row = b*32 + (t>>3), 8 threads/row, 16 cols each
      const int w = b*32 + (t >> 3);
      const float* mw = move + w*128 + (t & 7)*16;
      float4 m0 = *(const float4*)(mw),   m1 = *(const float4*)(mw+4);
      float4 m2 = *(const float4*)(mw+8), m3 = *(const float4*)(mw+12);
      float s1 = m0.x+m0.y+m0.z+m0.w + m1.x+m1.y+m1.z+m1.w
               + m2.x+m2.y+m2.z+m2.w + m3.x+m3.y+m3.z+m3.w;
      float s2 = m0.x*m0.x+m0.y*m0.y+m0.z*m0.z+m0.w*m0.w
               + m1.x*m1.x+m1.y*m1.y+m1.z*m1.z+m1.w*m1.w
               + m2.x*m2.x+m2.y*m2.y+m2.z*m2.z+m2.w*m2.w
               + m3.x*m3.x+m3.y*m3.y+m3.z*m3.z+m3.w*m3.w;
      #pragma unroll
      for (int m = 1; m < 8; m <<= 1){ s1 += __shfl_xor(s1, m, 64); s2 += __shfl_xor(s2, m, 64); }
      if ((t & 7) == 0) SM[w] = make_float2(s1, s2);
      unsigned* dst = mbf + w*64 + (t & 7)*8;
      dst[0] = packbf(m0.x,m0.y); dst[1] = packbf(m0.z,m0.w);
      dst[2] = packbf(m1.x,m1.y); dst[3] = packbf(m1.z,m1.w);
      dst[4] = packbf(m2.x,m2.y); dst[5] = packbf(m2.z,m2.w);
      dst[6] = packbf(m3.x,m3.y); dst[7] = packbf(m3.z,m3.w);
    }
    if (t < 32){ partial[b*32 + t] = 0.f; out[b*32 + t] = 0.f; }
    if (b == 0 && t == 64) *logzdone = 0;   // reset flag each replay (stream-ordered)
  }
}

// ---------------------------------------------------------------------------
// Node 2: scan blocks (0..159) and logz blocks (160..255, grid-stride).
// logz blocks: tiles -> one RELEASE fetch_add(logzdone) -> EXIT (no spin).
// scan blocks: scan (which kept in LDS) -> one thread RELAXED-spins on
// logzdone (no cache-maintenance storm) -> acquire fence -> dots epilogue
// folded in (atomicAdd into out).
// ---------------------------------------------------------------------------
__global__ __launch_bounds__(256) void workdots_kernel(
    const unsigned short* __restrict__ Hh, const unsigned short* __restrict__ Lh,
    const unsigned short* __restrict__ Gh, const float2* __restrict__ SM,
    const float* __restrict__ HU0, const float* __restrict__ LU0,
    const float* __restrict__ D0, const float2* __restrict__ S0,
    const float* __restrict__ prefB, const float* __restrict__ rd,
    const unsigned* __restrict__ mbf, const float* __restrict__ vw,
    const float* __restrict__ vb, float* __restrict__ partial,
    const int* __restrict__ y, const float* __restrict__ move,
    float* __restrict__ out, int* __restrict__ logzdone)
{
  __shared__ float les[2048];               // logz reduce (8 KB)
  __shared__ int whichs[T_];
  const int bid = blockIdx.x, t = threadIdx.x;
  const int lane = t & 63, wv = t >> 6;
  const int c16 = lane & 15, q = lane >> 4;

  if (bid < NCHAIN){
    // ---------------- scan (wave 0 only) ----------------
    if (t < 64){
      const int c = bid, b = c / NS_;
      const int l = t, t0 = l*8;

      float HU[8], LU[8], D[8], prev1[8], bias[8];
      #pragma unroll
      for (int k = 0; k < 8; k += 4){
        float4 h = *(const float4*)(HU0 + b*ST_ + t0 + k);
        float4 u = *(const float4*)(LU0 + b*ST_ + t0 + k);
        float4 d = *(const float4*)(D0  + b*ST_ + t0 + k);
        float4 bb= *(const float4*)(prefB + t0 + k);
        HU[k]=h.x; HU[k+1]=h.y; HU[k+2]=h.z; HU[k+3]=h.w;
        LU[k]=u.x; LU[k+1]=u.y; LU[k+2]=u.z; LU[k+3]=u.w;
        D[k]=d.x;  D[k+1]=d.y;  D[k+2]=d.z;  D[k+3]=d.w;
        bias[k]=bb.x; bias[k+1]=bb.y; bias[k+2]=bb.z; bias[k+3]=bb.w;
      }
      #pragma unroll
      for (int k = 0; k < 8; ++k) prev1[k] = 0.f;
      float2 s0 = S0[b];
      float S1 = s0.x, S2 = s0.y;
      float rdreg = (l < T_) ? rd[l*(B_*NS_) + c] : 0.f;

      for (int st = 0; st < T_; ++st){
        const float mean = S1 * (1.f/128.f);
        const float var  = (S2 - 128.f*mean*mean) * (1.f/127.f);
        const float sc   = 0.113f / (1e-5f + sqrtf(var));

        float cum[8]; float run = 0.f;
        #pragma unroll
        for (int k = 0; k < 8; ++k){
          float pref = fmaf(sc, HU[k], prev1[k] + bias[k]);
          run += __expf(pref);
          cum[k] = run;
        }
        float incl = run;
        DPPADD(incl, 0x111, 0xf)
        DPPADD(incl, 0x112, 0xf)
        DPPADD(incl, 0x114, 0xf)
        DPPADD(incl, 0x118, 0xf)
        DPPADD(incl, 0x142, 0xa)
        DPPADD(incl, 0x143, 0xc)
        const float total  = readlane_f(incl, 63);
        const float target = readlane_f(rdreg, st) * total;

        const bool cond = target < incl;
        const unsigned long long bal = __ballot(cond);
        const float excl = incl - run;
        int kw = 7; float dcand = D[7];
        #pragma unroll
        for (int k = 6; k >= 0; --k){
          bool ck = target < excl + cum[k];
          kw = ck ? k : kw;
          dcand = ck ? D[k] : dcand;
        }
        int which; float dW;
        if (bal){
          const int wlane = __ffsll(bal) - 1;
          which = __builtin_amdgcn_readlane(t0 + kw, wlane);
          dW    = readlane_f(dcand, wlane);
        } else {
          which = 0;
          dW    = readlane_f(D[0], 0);
        }
        if (l == 0) whichs[st] = which;

        const int rb = which*ST_ + t0;
        const uint4 hq = *(const uint4*)(Hh + rb);
        const uint4 lq = *(const uint4*)(Lh + rb);
        const uint4 gq = *(const uint4*)(Gh + rb);
        const float2 sm = SM[which];
        const unsigned ha[4] = {hq.x, hq.y, hq.z, hq.w};
        const unsigned la[4] = {lq.x, lq.y, lq.z, lq.w};
        const unsigned ga[4] = {gq.x, gq.y, gq.z, gq.w};
        #pragma unroll
        for (int k = 0; k < 8; ++k){
          const float Hk = h2f(ha[k>>1], k&1);
          const float Lk = h2f(la[k>>1], k&1);
          const float Gk = h2f(ga[k>>1], k&1);
          const float p1 = sc * LU[k];
          HU[k] = fmaf(sc, HU[k], Hk);
          LU[k] = p1 + Lk;
          D[k]  = fmaf(sc, D[k], Gk);
          prev1[k] = p1;
        }
        S1 = fmaf(sc, S1, sm.x);
        S2 = fmaf(sc*sc, S2, fmaf(2.f*sc, dW, sm.y));
      }
    }
    __syncthreads();                        // whichs visible block-wide

    // ---- wait for logz: RELAXED spin (no invalidates), one thread ----
    if (t == 0){
      while (__hip_atomic_load(logzdone, __ATOMIC_RELAXED,
                               __HIP_MEMORY_SCOPE_AGENT) < NLOGZ)
        __builtin_amdgcn_s_sleep(8);
    }
    __syncthreads();
    __builtin_amdgcn_fence(__ATOMIC_ACQUIRE, "agent");   // pair with release-add

    // ---------------- dots epilogue (all 4 waves, 8 steps each) ----------
    {
      const int b = bid / NS_;
      #pragma unroll
      for (int k = 0; k < 8; ++k){
        const int st = wv*8 + k;
        const int w  = whichs[st];
        const int yr = y[b*T_ + st];
        float dot = move[w*D_ + lane]      * vw[yr*D_ + lane]
                  + move[w*D_ + 64 + lane] * vw[yr*D_ + 64 + lane];
        #pragma unroll
        for (int m = 1; m < 64; m <<= 1) dot += __shfl_xor(dot, m, 64);
        if (lane == 0)
          atomicAdd(&out[b*T_ + st],
                    (dot - __logf(partial[w]) + vb[yr]) * (1.f/NS_));
      }
    }
  } else {
    // ---------------- logz (grid-stride 250 tiles over 96 blocks) --------
    const char* mb = (const char*)mbf;
    for (int u = bid - NCHAIN; u < 250; u += NLOGZ){
      const int vbase = u*128 + wv*32;
      short8 afr[2][4];
      float vbr[2][4];
      #pragma unroll
      for (int vt = 0; vt < 2; ++vt){
        const int vr = vbase + vt*16 + c16;
        const float* wp = vw + vr*D_ + q*8;
        #pragma unroll
        for (int kk = 0; kk < 4; ++kk){
          float4 f0 = *(const float4*)(wp + kk*32);
          float4 f1 = *(const float4*)(wp + kk*32 + 4);
          short8 a;
          a[0]=(short)f2bf(f0.x); a[1]=(short)f2bf(f0.y);
          a[2]=(short)f2bf(f0.z); a[3]=(short)f2bf(f0.w);
          a[4]=(short)f2bf(f1.x); a[5]=(short)f2bf(f1.y);
          a[6]=(short)f2bf(f1.z); a[7]=(short)f2bf(f1.w);
          afr[vt][kk] = a;
        }
        #pragma unroll
        for (int r = 0; r < 4; ++r)
          vbr[vt][r] = vb[vbase + vt*16 + q*4 + r];
      }

      float esl[32];
      #pragma unroll
      for (int s = 0; s < 32; ++s) esl[s] = 0.f;

      #pragma unroll
      for (int s = 0; s < 32; ++s){
        short8 bfr[4];
        #pragma unroll
        for (int kk = 0; kk < 4; ++kk){
          const int row = s*16 + c16;
          bfr[kk] = *(const short8*)(mb + row*256 + q*16 + kk*64);
        }
        #pragma unroll
        for (int vt = 0; vt < 2; ++vt){
          f32x4 acc = {0.f,0.f,0.f,0.f};
          #pragma unroll
          for (int kk = 0; kk < 4; ++kk)
            acc = __builtin_amdgcn_mfma_f32_16x16x32_bf16(afr[vt][kk], bfr[kk], acc, 0, 0, 0);
          #pragma unroll
          for (int r = 0; r < 4; ++r)
            esl[s] += __expf(acc[r] + vbr[vt][r]);
        }
      }
      #pragma unroll
      for (int s = 0; s < 32; ++s){
        esl[s] += __shfl_xor(esl[s], 16, 64);
        esl[s] += __shfl_xor(esl[s], 32, 64);
      }
      if (lane < 16){
        #pragma unroll
        for (int s = 0; s < 32; ++s) les[wv*512 + s*16 + lane] = esl[s];
      }
      __syncthreads();
      #pragma unroll
      for (int i = 0; i < 2; ++i){
        const int st = t + i*256;
        atomicAdd(&partial[st], les[st] + les[512+st] + les[1024+st] + les[1536+st]);
      }
      __syncthreads();     // les reused next tile
    }
    // publish: all partial adds done -> one release increment, then exit
    if (t == 0)
      __hip_atomic_fetch_add(logzdone, 1, __ATOMIC_RELEASE,
                             __HIP_MEMORY_SCOPE_AGENT);
  }
}

extern "C" void kernel_launch(void* const* d_in, const int* in_sizes, int n_in,
                              void* d_out, int out_size, void* d_ws, size_t ws_size,
                              hipStream_t stream)
{
  const int*   zi     = (const int*)d_in[0];
  const int*   y      = (const int*)d_in[1];
  const float* rd     = (const float*)d_in[2];
  const float* latent = (const float*)d_in[3];
  const float* prefW  = (const float*)d_in[4];
  const float* prefB  = (const float*)d_in[5];
  const float* move   = (const float*)d_in[6];
  const float* vw     = (const float*)d_in[7];
  const float* vb     = (const float*)d_in[8];
  float* out = (float*)d_out;

  char* ws = (char*)d_ws;
  unsigned short* Hh = (unsigned short*)(ws);           // 512 KB
  unsigned short* Lh = (unsigned short*)(ws + 524288);  // 512 KB
  unsigned short* Gh = (unsigned short*)(ws + 1048576); // 512 KB
  float2* SM    = (float2*)(ws + 1572864);              // 4 KB
  float*  HU0   = (float*)(ws + 1576960);               // 32 KB
  float*  LU0   = (float*)(ws + 1609728);               // 32 KB
  float*  D0    = (float*)(ws + 1642496);               // 32 KB
  float2* S0    = (float2*)(ws + 1675264);              // 128 B
  float*  partial = (float*)(ws + 1675392);             // 2 KB
  unsigned* mbf = (unsigned*)(ws + 1697920);            // 128 KB (bf16 move)
  int*    logzdone = (int*)(ws + 1828992);              // 4 B flag

  hipLaunchKernelGGL(prep_kernel, dim3(208), dim3(256), 0, stream,
                     zi, latent, prefW, move, Hh, Lh, Gh,
                     HU0, LU0, D0, S0, SM, mbf, partial, out, logzdone);
  hipLaunchKernelGGL(workdots_kernel, dim3(NBLK2), dim3(256), 0, stream,
                     Hh, Lh, Gh, SM, HU0, LU0, D0, S0, prefB, rd,
                     mbf, vw, vb, partial, y, move, out, logzdone);
}

// Round 12
// 82.257 us; speedup vs baseline: 2.6646x; 1.2422x over previous
//
#include <hip/hip_runtime.h>
#include <hip/hip_bf16.h>

#define B_ 16
#define T_ 32
#define NS_ 10
#define D_ 128
#define ST_ 512
#define V_ 32000
#define NCHAIN 160
#define NBLK2 256                // node-2 grid: 1 block/CU, all resident
#define NLOGZ (NBLK2 - NCHAIN)   // 96 logz blocks
#define NTILE 250                // 250 tiles x 128 vocab rows

using short8  = __attribute__((ext_vector_type(8))) short;
using f32x4   = __attribute__((ext_vector_type(4))) float;
using half8   = __attribute__((ext_vector_type(8))) _Float16;
using half2v  = __attribute__((ext_vector_type(2))) _Float16;

__device__ __forceinline__ unsigned short f2bf(float f){
  unsigned u = __float_as_uint(f);
  u += 0x7FFFu + ((u >> 16) & 1u);          // RNE to bf16
  return (unsigned short)(u >> 16);
}
__device__ __forceinline__ unsigned packbf(float a, float b){
  return ((unsigned)f2bf(b) << 16) | (unsigned)f2bf(a);
}
__device__ __forceinline__ unsigned short f2h(float f){
  return __builtin_bit_cast(unsigned short, (_Float16)f);
}
__device__ __forceinline__ float h2f(unsigned u, int hi){
  half2v h = __builtin_bit_cast(half2v, u);
  return (float)h[hi];
}
__device__ __forceinline__ float readlane_f(float v, int lane){
  return __int_as_float(__builtin_amdgcn_readlane(__float_as_int(v), lane));
}

// wave64 inclusive scan via DPP: 6 ops
#define DPPADD(x, ctrl, rm) { \
  int _t = __builtin_amdgcn_update_dpp(0, __float_as_int(x), ctrl, rm, 0xf, true); \
  x += __int_as_float(_t); }

// ---------------------------------------------------------------------------
// Node 1: prep. 208 blocks x 256 thr.
//  blocks 0..191 : tables  C[w][ct] = move_w . Brow(ct) (f16 MFMA -> Hh/Lh/Gh)
//  blocks 192..207: per-batch init + SM + mbf + zero partial/out/flags
// ---------------------------------------------------------------------------
__global__ __launch_bounds__(256) void prep_kernel(
    const int* __restrict__ zi, const float* __restrict__ latent,
    const float* __restrict__ prefW, const float* __restrict__ move,
    unsigned short* __restrict__ Hh, unsigned short* __restrict__ Lh,
    unsigned short* __restrict__ Gh,
    float* __restrict__ HU0, float* __restrict__ LU0, float* __restrict__ D0,
    float2* __restrict__ S0, float2* __restrict__ SM,
    unsigned* __restrict__ mbf, float* __restrict__ partial,
    float* __restrict__ out, int* __restrict__ logzdone,
    int* __restrict__ scandone)
{
  const int bid = blockIdx.x, t = threadIdx.x;
  const int lane = t & 63, wv = t >> 6;
  const int c16 = lane & 15, q = lane >> 4;

  if (bid < 192){
    const int sg = bid / 24, tile = bid % 24;
    half8 afr[4][4];
    #pragma unroll
    for (int rt = 0; rt < 4; ++rt){
      const float* mp = move + (sg*64 + rt*16 + c16)*D_ + q*8;
      #pragma unroll
      for (int kk = 0; kk < 4; ++kk){
        float4 f0 = *(const float4*)(mp + kk*32);
        float4 f1 = *(const float4*)(mp + kk*32 + 4);
        half8 a;
        a[0]=(_Float16)f0.x; a[1]=(_Float16)f0.y; a[2]=(_Float16)f0.z; a[3]=(_Float16)f0.w;
        a[4]=(_Float16)f1.x; a[5]=(_Float16)f1.y; a[6]=(_Float16)f1.z; a[7]=(_Float16)f1.w;
        afr[rt][kk] = a;
      }
    }
    const int ct = tile*64 + wv*16 + c16;     // 64-tiles never straddle 512-bounds
    const float* bp; unsigned short* base; int ccol;
    if (ct < 512)      { bp = prefW + ct*256 + 128; base = Hh; ccol = ct; }
    else if (ct < 1024){ bp = prefW + (ct-512)*256; base = Lh; ccol = ct-512; }
    else               { bp = move + (ct-1024)*128; base = Gh; ccol = ct-1024; }
    half8 bfr[4];
    #pragma unroll
    for (int kk = 0; kk < 4; ++kk){
      float4 f0 = *(const float4*)(bp + q*8 + kk*32);
      float4 f1 = *(const float4*)(bp + q*8 + kk*32 + 4);
      half8 bb;
      bb[0]=(_Float16)f0.x; bb[1]=(_Float16)f0.y; bb[2]=(_Float16)f0.z; bb[3]=(_Float16)f0.w;
      bb[4]=(_Float16)f1.x; bb[5]=(_Float16)f1.y; bb[6]=(_Float16)f1.z; bb[7]=(_Float16)f1.w;
      bfr[kk] = bb;
    }
    #pragma unroll
    for (int rt = 0; rt < 4; ++rt){
      f32x4 acc = {0.f,0.f,0.f,0.f};
      #pragma unroll
      for (int kk = 0; kk < 4; ++kk)
        acc = __builtin_amdgcn_mfma_f32_16x16x32_f16(afr[rt][kk], bfr[kk], acc, 0, 0, 0);
      #pragma unroll
      for (int r = 0; r < 4; ++r){
        const int w = sg*64 + rt*16 + q*4 + r;
        base[w*ST_ + ccol] = f2h(acc[r]);
      }
    }
  } else {
    const int b = bid - 192;
    __shared__ float zl[128];
    if (t < 128) zl[t] = latent[zi[b]*D_ + t];
    __syncthreads();

    #pragma unroll
    for (int ii = 0; ii < 2; ++ii){
      const int sidx = t + ii*256;
      const float* wr = prefW + sidx*256;
      const float* mv = move + sidx*128;
      float hu = 0.f, lu = 0.f, d0 = 0.f;
      #pragma unroll 8
      for (int j = 0; j < 128; j += 4){
        float4 w0 = *(const float4*)(wr + j);
        float4 w1 = *(const float4*)(wr + 128 + j);
        float4 m  = *(const float4*)(mv + j);
        float4 z  = *(const float4*)(&zl[j]);
        lu += w0.x*z.x + w0.y*z.y + w0.z*z.z + w0.w*z.w;
        hu += w1.x*z.x + w1.y*z.y + w1.z*z.z + w1.w*z.w;
        d0 += m.x*z.x + m.y*z.y + m.z*z.z + m.w*z.w;
      }
      HU0[b*ST_ + sidx] = hu; LU0[b*ST_ + sidx] = lu; D0[b*ST_ + sidx] = d0;
    }
    if (t < 64){
      float a = zl[t], bb = zl[t + 64];
      float s1 = a + bb, s2 = a*a + bb*bb;
      #pragma unroll
      for (int m = 1; m < 64; m <<= 1){ s1 += __shfl_xor(s1, m, 64); s2 += __shfl_xor(s2, m, 64); }
      if (t == 0) S0[b] = make_float2(s1, s2);
    }
    { // SM + mbf: row = b*32 + (t>>3), 8 threads/row, 16 cols each
      const int w = b*32 + (t >> 3);
      const float* mw = move + w*128 + (t & 7)*16;
      float4 m0 = *(const float4*)(mw),   m1 = *(const float4*)(mw+4);
      float4 m2 = *(const float4*)(mw+8), m3 = *(const float4*)(mw+12);
      float s1 = m0.x+m0.y+m0.z+m0.w + m1.x+m1.y+m1.z+m1.w
               + m2.x+m2.y+m2.z+m2.w + m3.x+m3.y+m3.z+m3.w;
      float s2 = m0.x*m0.x+m0.y*m0.y+m0.z*m0.z+m0.w*m0.w
               + m1.x*m1.x+m1.y*m1.y+m1.z*m1.z+m1.w*m1.w
               + m2.x*m2.x+m2.y*m2.y+m2.z*m2.z+m2.w*m2.w
               + m3.x*m3.x+m3.y*m3.y+m3.z*m3.z+m3.w*m3.w;
      #pragma unroll
      for (int m = 1; m < 8; m <<= 1){ s1 += __shfl_xor(s1, m, 64); s2 += __shfl_xor(s2, m, 64); }
      if ((t & 7) == 0) SM[w] = make_float2(s1, s2);
      unsigned* dst = mbf + w*64 + (t & 7)*8;
      dst[0] = packbf(m0.x,m0.y); dst[1] = packbf(m0.z,m0.w);
      dst[2] = packbf(m1.x,m1.y); dst[3] = packbf(m1.z,m1.w);
      dst[4] = packbf(m2.x,m2.y); dst[5] = packbf(m2.z,m2.w);
      dst[6] = packbf(m3.x,m3.y); dst[7] = packbf(m3.z,m3.w);
    }
    if (t < 32){ partial[b*32 + t] = 0.f; out[b*32 + t] = 0.f; }
    if (b == 0 && t == 64) *logzdone = 0;   // reset flags each replay (stream-ordered)
    if (b == 0 && t == 65) *scandone = 0;
  }
}

// ---------------------------------------------------------------------------
// Node 2: 256 blocks. No block spins except the LAST logz block.
//  scan blocks (0..159): scan -> publish which + release scandone ->
//                        dot-part epilogue (atomicAdd out) -> EXIT.
//  logz blocks (160..255): LDS-stage mbf (XOR swizzle) -> 2-3 tiles ->
//                          ticket = fetch_add(logzdone). LAST ticket holder
//                          waits scandone (already done), adds -log(partial)/NS.
// ---------------------------------------------------------------------------
__global__ __launch_bounds__(256) void workdots_kernel(
    const unsigned short* __restrict__ Hh, const unsigned short* __restrict__ Lh,
    const unsigned short* __restrict__ Gh, const float2* __restrict__ SM,
    const float* __restrict__ HU0, const float* __restrict__ LU0,
    const float* __restrict__ D0, const float2* __restrict__ S0,
    const float* __restrict__ prefB, const float* __restrict__ rd,
    int* __restrict__ whichOut,
    const unsigned* __restrict__ mbf, const float* __restrict__ vw,
    const float* __restrict__ vb, float* __restrict__ partial,
    const int* __restrict__ y, const float* __restrict__ move,
    float* __restrict__ out, int* __restrict__ logzdone,
    int* __restrict__ scandone)
{
  extern __shared__ __align__(16) char lsm[];   // 128 KB mbf stage (logz only)
  __shared__ float les[2048];                   // logz reduce (8 KB)
  __shared__ int whichs[T_];
  __shared__ int lastFlag;
  const int bid = blockIdx.x, t = threadIdx.x;
  const int lane = t & 63, wv = t >> 6;
  const int c16 = lane & 15, q = lane >> 4;

  if (bid < NCHAIN){
    // ---------------- scan (wave 0 only) ----------------
    if (t < 64){
      const int c = bid, b = c / NS_;
      const int l = t, t0 = l*8;

      float HU[8], LU[8], D[8], prev1[8], bias[8];
      #pragma unroll
      for (int k = 0; k < 8; k += 4){
        float4 h = *(const float4*)(HU0 + b*ST_ + t0 + k);
        float4 u = *(const float4*)(LU0 + b*ST_ + t0 + k);
        float4 d = *(const float4*)(D0  + b*ST_ + t0 + k);
        float4 bb= *(const float4*)(prefB + t0 + k);
        HU[k]=h.x; HU[k+1]=h.y; HU[k+2]=h.z; HU[k+3]=h.w;
        LU[k]=u.x; LU[k+1]=u.y; LU[k+2]=u.z; LU[k+3]=u.w;
        D[k]=d.x;  D[k+1]=d.y;  D[k+2]=d.z;  D[k+3]=d.w;
        bias[k]=bb.x; bias[k+1]=bb.y; bias[k+2]=bb.z; bias[k+3]=bb.w;
      }
      #pragma unroll
      for (int k = 0; k < 8; ++k) prev1[k] = 0.f;
      float2 s0 = S0[b];
      float S1 = s0.x, S2 = s0.y;
      float rdreg = (l < T_) ? rd[l*(B_*NS_) + c] : 0.f;

      for (int st = 0; st < T_; ++st){
        const float mean = S1 * (1.f/128.f);
        const float var  = (S2 - 128.f*mean*mean) * (1.f/127.f);
        const float sc   = 0.113f / (1e-5f + sqrtf(var));

        float cum[8]; float run = 0.f;
        #pragma unroll
        for (int k = 0; k < 8; ++k){
          float pref = fmaf(sc, HU[k], prev1[k] + bias[k]);
          run += __expf(pref);
          cum[k] = run;
        }
        float incl = run;
        DPPADD(incl, 0x111, 0xf)
        DPPADD(incl, 0x112, 0xf)
        DPPADD(incl, 0x114, 0xf)
        DPPADD(incl, 0x118, 0xf)
        DPPADD(incl, 0x142, 0xa)
        DPPADD(incl, 0x143, 0xc)
        const float total  = readlane_f(incl, 63);
        const float target = readlane_f(rdreg, st) * total;

        const bool cond = target < incl;
        const unsigned long long bal = __ballot(cond);
        const float excl = incl - run;
        int kw = 7; float dcand = D[7];
        #pragma unroll
        for (int k = 6; k >= 0; --k){
          bool ck = target < excl + cum[k];
          kw = ck ? k : kw;
          dcand = ck ? D[k] : dcand;
        }
        int which; float dW;
        if (bal){
          const int wlane = __ffsll(bal) - 1;
          which = __builtin_amdgcn_readlane(t0 + kw, wlane);
          dW    = readlane_f(dcand, wlane);
        } else {
          which = 0;
          dW    = readlane_f(D[0], 0);
        }
        if (l == 0){ whichs[st] = which; whichOut[c*T_ + st] = which; }

        const int rb = which*ST_ + t0;
        const uint4 hq = *(const uint4*)(Hh + rb);
        const uint4 lq = *(const uint4*)(Lh + rb);
        const uint4 gq = *(const uint4*)(Gh + rb);
        const float2 sm = SM[which];
        const unsigned ha[4] = {hq.x, hq.y, hq.z, hq.w};
        const unsigned la[4] = {lq.x, lq.y, lq.z, lq.w};
        const unsigned ga[4] = {gq.x, gq.y, gq.z, gq.w};
        #pragma unroll
        for (int k = 0; k < 8; ++k){
          const float Hk = h2f(ha[k>>1], k&1);
          const float Lk = h2f(la[k>>1], k&1);
          const float Gk = h2f(ga[k>>1], k&1);
          const float p1 = sc * LU[k];
          HU[k] = fmaf(sc, HU[k], Hk);
          LU[k] = p1 + Lk;
          D[k]  = fmaf(sc, D[k], Gk);
          prev1[k] = p1;
        }
        S1 = fmaf(sc, S1, sm.x);
        S2 = fmaf(sc*sc, S2, fmaf(2.f*sc, dW, sm.y));
      }
    }
    __syncthreads();                        // whichs / whichOut writes done

    if (t == 0){
      __threadfence();                      // release whichOut
      __hip_atomic_fetch_add(scandone, 1, __ATOMIC_RELEASE,
                             __HIP_MEMORY_SCOPE_AGENT);
    }

    // ------- dot-part epilogue (no partial needed): all 4 waves -------
    {
      const int b = bid / NS_;
      #pragma unroll
      for (int k = 0; k < 8; ++k){
        const int st = wv*8 + k;
        const int w  = whichs[st];
        const int yr = y[b*T_ + st];
        float dot = move[w*D_ + lane]      * vw[yr*D_ + lane]
                  + move[w*D_ + 64 + lane] * vw[yr*D_ + 64 + lane];
        #pragma unroll
        for (int m = 1; m < 64; m <<= 1) dot += __shfl_xor(dot, m, 64);
        if (lane == 0)
          atomicAdd(&out[b*T_ + st], (dot + vb[yr]) * (1.f/NS_));
      }
    }
  } else {
    // ---------------- logz: stage mbf -> tiles -> ticket ----------------
    for (int i = t; i < ST_*64; i += 256){
      const int row = i >> 6, colu = i & 63;
      unsigned byte = row*256 + colu*4;
      byte ^= ((row & 7) << 4);
      *(unsigned*)(lsm + byte) = mbf[i];
    }
    __syncthreads();

    for (int u = bid - NCHAIN; u < NTILE; u += NLOGZ){
      const int vbase = u*128 + wv*32;
      short8 afr[2][4];
      float vbr[2][4];
      #pragma unroll
      for (int vt = 0; vt < 2; ++vt){
        const int vr = vbase + vt*16 + c16;
        const float* wp = vw + vr*D_ + q*8;
        #pragma unroll
        for (int kk = 0; kk < 4; ++kk){
          float4 f0 = *(const float4*)(wp + kk*32);
          float4 f1 = *(const float4*)(wp + kk*32 + 4);
          short8 a;
          a[0]=(short)f2bf(f0.x); a[1]=(short)f2bf(f0.y);
          a[2]=(short)f2bf(f0.z); a[3]=(short)f2bf(f0.w);
          a[4]=(short)f2bf(f1.x); a[5]=(short)f2bf(f1.y);
          a[6]=(short)f2bf(f1.z); a[7]=(short)f2bf(f1.w);
          afr[vt][kk] = a;
        }
        #pragma unroll
        for (int r = 0; r < 4; ++r)
          vbr[vt][r] = vb[vbase + vt*16 + q*4 + r];
      }

      #pragma unroll 2
      for (int s = 0; s < 32; ++s){
        short8 bfr[4];
        #pragma unroll
        for (int kk = 0; kk < 4; ++kk){
          const int row = s*16 + c16;
          unsigned byte = row*256 + (q*8 + kk*32)*2;
          byte ^= ((row & 7) << 4);
          bfr[kk] = *(const short8*)(lsm + byte);
        }
        float es = 0.f;
        #pragma unroll
        for (int vt = 0; vt < 2; ++vt){
          f32x4 acc = {0.f,0.f,0.f,0.f};
          #pragma unroll
          for (int kk = 0; kk < 4; ++kk)
            acc = __builtin_amdgcn_mfma_f32_16x16x32_bf16(afr[vt][kk], bfr[kk], acc, 0, 0, 0);
          #pragma unroll
          for (int r = 0; r < 4; ++r)
            es += __expf(acc[r] + vbr[vt][r]);
        }
        es += __shfl_xor(es, 16, 64);
        es += __shfl_xor(es, 32, 64);
        if (lane < 16) les[wv*512 + s*16 + lane] = es;
      }
      __syncthreads();
      #pragma unroll
      for (int i = 0; i < 2; ++i){
        const int st = t + i*256;
        atomicAdd(&partial[st], les[st] + les[512+st] + les[1024+st] + les[1536+st]);
      }
      __syncthreads();     // les reused next tile
    }

    // ---- ticket: last finisher does the -log(partial) epilogue ----
    if (t == 0){
      const int ticket = __hip_atomic_fetch_add(logzdone, 1, __ATOMIC_ACQ_REL,
                                                __HIP_MEMORY_SCOPE_AGENT);
      lastFlag = (ticket == NLOGZ - 1);
    }
    __syncthreads();
    if (lastFlag){
      if (t == 0){
        while (__hip_atomic_load(scandone, __ATOMIC_RELAXED,
                                 __HIP_MEMORY_SCOPE_AGENT) < NCHAIN)
          __builtin_amdgcn_s_sleep(8);
      }
      __syncthreads();
      __builtin_amdgcn_fence(__ATOMIC_ACQUIRE, "agent");
      for (int p = t; p < B_*T_; p += 256){
        const int b = p >> 5, st = p & 31;
        float ls = 0.f;
        #pragma unroll
        for (int s = 0; s < NS_; ++s)
          ls += __logf(partial[whichOut[(b*NS_ + s)*T_ + st]]);
        atomicAdd(&out[b*T_ + st], -ls * (1.f/NS_));
      }
    }
  }
}

extern "C" void kernel_launch(void* const* d_in, const int* in_sizes, int n_in,
                              void* d_out, int out_size, void* d_ws, size_t ws_size,
                              hipStream_t stream)
{
  const int*   zi     = (const int*)d_in[0];
  const int*   y      = (const int*)d_in[1];
  const float* rd     = (const float*)d_in[2];
  const float* latent = (const float*)d_in[3];
  const float* prefW  = (const float*)d_in[4];
  const float* prefB  = (const float*)d_in[5];
  const float* move   = (const float*)d_in[6];
  const float* vw     = (const float*)d_in[7];
  const float* vb     = (const float*)d_in[8];
  float* out = (float*)d_out;

  char* ws = (char*)d_ws;
  unsigned short* Hh = (unsigned short*)(ws);           // 512 KB
  unsigned short* Lh = (unsigned short*)(ws + 524288);  // 512 KB
  unsigned short* Gh = (unsigned short*)(ws + 1048576); // 512 KB
  float2* SM    = (float2*)(ws + 1572864);              // 4 KB
  float*  HU0   = (float*)(ws + 1576960);               // 32 KB
  float*  LU0   = (float*)(ws + 1609728);               // 32 KB
  float*  D0    = (float*)(ws + 1642496);               // 32 KB
  float2* S0    = (float2*)(ws + 1675264);              // 128 B
  float*  partial = (float*)(ws + 1675392);             // 2 KB
  int*    which = (int*)(ws + 1677440);                 // 20 KB
  unsigned* mbf = (unsigned*)(ws + 1697920);            // 128 KB (bf16 move)
  int*    logzdone = (int*)(ws + 1828992);              // flags
  int*    scandone = (int*)(ws + 1828996);

  static const int work_lds = 131072;                   // dynamic: mbf stage
  hipFuncSetAttribute((const void*)workdots_kernel,
                      hipFuncAttributeMaxDynamicSharedMemorySize, work_lds);

  hipLaunchKernelGGL(prep_kernel, dim3(208), dim3(256), 0, stream,
                     zi, latent, prefW, move, Hh, Lh, Gh,
                     HU0, LU0, D0, S0, SM, mbf, partial, out,
                     logzdone, scandone);
  hipLaunchKernelGGL(workdots_kernel, dim3(NBLK2), dim3(256), work_lds, stream,
                     Hh, Lh, Gh, SM, HU0, LU0, D0, S0, prefB, rd, which,
                     mbf, vw, vb, partial, y, move, out, logzdone, scandone);
}

// Round 13
// 74.906 us; speedup vs baseline: 2.9260x; 1.0981x over previous
//
#include <hip/hip_runtime.h>
#include <hip/hip_bf16.h>

#define B_ 16
#define T_ 32
#define NS_ 10
#define D_ 128
#define ST_ 512
#define V_ 32000
#define NCHAIN 160
#define NLOGZ 250                // one 128-row vocab tile per logz block
#define NBLK2 (NCHAIN + NLOGZ)   // 410 blocks, ~8.7KB LDS each -> all resident

using short8  = __attribute__((ext_vector_type(8))) short;
using f32x4   = __attribute__((ext_vector_type(4))) float;
using half8   = __attribute__((ext_vector_type(8))) _Float16;
using half2v  = __attribute__((ext_vector_type(2))) _Float16;

__device__ __forceinline__ unsigned short f2bf(float f){
  unsigned u = __float_as_uint(f);
  u += 0x7FFFu + ((u >> 16) & 1u);          // RNE to bf16
  return (unsigned short)(u >> 16);
}
__device__ __forceinline__ unsigned packbf(float a, float b){
  return ((unsigned)f2bf(b) << 16) | (unsigned)f2bf(a);
}
__device__ __forceinline__ unsigned short f2h(float f){
  return __builtin_bit_cast(unsigned short, (_Float16)f);
}
__device__ __forceinline__ float h2f(unsigned u, int hi){
  half2v h = __builtin_bit_cast(half2v, u);
  return (float)h[hi];
}
__device__ __forceinline__ float readlane_f(float v, int lane){
  return __int_as_float(__builtin_amdgcn_readlane(__float_as_int(v), lane));
}

// wave64 inclusive scan via DPP: 6 ops
#define DPPADD(x, ctrl, rm) { \
  int _t = __builtin_amdgcn_update_dpp(0, __float_as_int(x), ctrl, rm, 0xf, true); \
  x += __int_as_float(_t); }

// ---------------------------------------------------------------------------
// Node 1: prep. 208 blocks x 256 thr.
//  blocks 0..191 : tables  C[w][ct] = move_w . Brow(ct) (f16 MFMA -> Hh/Lh/Gh)
//  blocks 192..207: per-batch init + SM + mbf + zero partial/out/flags
// ---------------------------------------------------------------------------
__global__ __launch_bounds__(256) void prep_kernel(
    const int* __restrict__ zi, const float* __restrict__ latent,
    const float* __restrict__ prefW, const float* __restrict__ move,
    unsigned short* __restrict__ Hh, unsigned short* __restrict__ Lh,
    unsigned short* __restrict__ Gh,
    float* __restrict__ HU0, float* __restrict__ LU0, float* __restrict__ D0,
    float2* __restrict__ S0, float2* __restrict__ SM,
    unsigned* __restrict__ mbf, float* __restrict__ partial,
    float* __restrict__ out, int* __restrict__ logzdone,
    int* __restrict__ scandone)
{
  const int bid = blockIdx.x, t = threadIdx.x;
  const int lane = t & 63, wv = t >> 6;
  const int c16 = lane & 15, q = lane >> 4;

  if (bid < 192){
    const int sg = bid / 24, tile = bid % 24;
    half8 afr[4][4];
    #pragma unroll
    for (int rt = 0; rt < 4; ++rt){
      const float* mp = move + (sg*64 + rt*16 + c16)*D_ + q*8;
      #pragma unroll
      for (int kk = 0; kk < 4; ++kk){
        float4 f0 = *(const float4*)(mp + kk*32);
        float4 f1 = *(const float4*)(mp + kk*32 + 4);
        half8 a;
        a[0]=(_Float16)f0.x; a[1]=(_Float16)f0.y; a[2]=(_Float16)f0.z; a[3]=(_Float16)f0.w;
        a[4]=(_Float16)f1.x; a[5]=(_Float16)f1.y; a[6]=(_Float16)f1.z; a[7]=(_Float16)f1.w;
        afr[rt][kk] = a;
      }
    }
    const int ct = tile*64 + wv*16 + c16;     // 64-tiles never straddle 512-bounds
    const float* bp; unsigned short* base; int ccol;
    if (ct < 512)      { bp = prefW + ct*256 + 128; base = Hh; ccol = ct; }
    else if (ct < 1024){ bp = prefW + (ct-512)*256; base = Lh; ccol = ct-512; }
    else               { bp = move + (ct-1024)*128; base = Gh; ccol = ct-1024; }
    half8 bfr[4];
    #pragma unroll
    for (int kk = 0; kk < 4; ++kk){
      float4 f0 = *(const float4*)(bp + q*8 + kk*32);
      float4 f1 = *(const float4*)(bp + q*8 + kk*32 + 4);
      half8 bb;
      bb[0]=(_Float16)f0.x; bb[1]=(_Float16)f0.y; bb[2]=(_Float16)f0.z; bb[3]=(_Float16)f0.w;
      bb[4]=(_Float16)f1.x; bb[5]=(_Float16)f1.y; bb[6]=(_Float16)f1.z; bb[7]=(_Float16)f1.w;
      bfr[kk] = bb;
    }
    #pragma unroll
    for (int rt = 0; rt < 4; ++rt){
      f32x4 acc = {0.f,0.f,0.f,0.f};
      #pragma unroll
      for (int kk = 0; kk < 4; ++kk)
        acc = __builtin_amdgcn_mfma_f32_16x16x32_f16(afr[rt][kk], bfr[kk], acc, 0, 0, 0);
      #pragma unroll
      for (int r = 0; r < 4; ++r){
        const int w = sg*64 + rt*16 + q*4 + r;
        base[w*ST_ + ccol] = f2h(acc[r]);
      }
    }
  } else {
    const int b = bid - 192;
    __shared__ float zl[128];
    if (t < 128) zl[t] = latent[zi[b]*D_ + t];
    __syncthreads();

    #pragma unroll
    for (int ii = 0; ii < 2; ++ii){
      const int sidx = t + ii*256;
      const float* wr = prefW + sidx*256;
      const float* mv = move + sidx*128;
      float hu = 0.f, lu = 0.f, d0 = 0.f;
      #pragma unroll 8
      for (int j = 0; j < 128; j += 4){
        float4 w0 = *(const float4*)(wr + j);
        float4 w1 = *(const float4*)(wr + 128 + j);
        float4 m  = *(const float4*)(mv + j);
        float4 z  = *(const float4*)(&zl[j]);
        lu += w0.x*z.x + w0.y*z.y + w0.z*z.z + w0.w*z.w;
        hu += w1.x*z.x + w1.y*z.y + w1.z*z.z + w1.w*z.w;
        d0 += m.x*z.x + m.y*z.y + m.z*z.z + m.w*z.w;
      }
      HU0[b*ST_ + sidx] = hu; LU0[b*ST_ + sidx] = lu; D0[b*ST_ + sidx] = d0;
    }
    if (t < 64){
      float a = zl[t], bb = zl[t + 64];
      float s1 = a + bb, s2 = a*a + bb*bb;
      #pragma unroll
      for (int m = 1; m < 64; m <<= 1){ s1 += __shfl_xor(s1, m, 64); s2 += __shfl_xor(s2, m, 64); }
      if (t == 0) S0[b] = make_float2(s1, s2);
    }
    { // SM + mbf: row = b*32 + (t>>3), 8 threads/row, 16 cols each
      const int w = b*32 + (t >> 3);
      const float* mw = move + w*128 + (t & 7)*16;
      float4 m0 = *(const float4*)(mw),   m1 = *(const float4*)(mw+4);
      float4 m2 = *(const float4*)(mw+8), m3 = *(const float4*)(mw+12);
      float s1 = m0.x+m0.y+m0.z+m0.w + m1.x+m1.y+m1.z+m1.w
               + m2.x+m2.y+m2.z+m2.w + m3.x+m3.y+m3.z+m3.w;
      float s2 = m0.x*m0.x+m0.y*m0.y+m0.z*m0.z+m0.w*m0.w
               + m1.x*m1.x+m1.y*m1.y+m1.z*m1.z+m1.w*m1.w
               + m2.x*m2.x+m2.y*m2.y+m2.z*m2.z+m2.w*m2.w
               + m3.x*m3.x+m3.y*m3.y+m3.z*m3.z+m3.w*m3.w;
      #pragma unroll
      for (int m = 1; m < 8; m <<= 1){ s1 += __shfl_xor(s1, m, 64); s2 += __shfl_xor(s2, m, 64); }
      if ((t & 7) == 0) SM[w] = make_float2(s1, s2);
      unsigned* dst = mbf + w*64 + (t & 7)*8;
      dst[0] = packbf(m0.x,m0.y); dst[1] = packbf(m0.z,m0.w);
      dst[2] = packbf(m1.x,m1.y); dst[3] = packbf(m1.z,m1.w);
      dst[4] = packbf(m2.x,m2.y); dst[5] = packbf(m2.z,m2.w);
      dst[6] = packbf(m3.x,m3.y); dst[7] = packbf(m3.z,m3.w);
    }
    if (t < 32){ partial[b*32 + t] = 0.f; out[b*32 + t] = 0.f; }
    if (b == 0 && t == 64) *logzdone = 0;   // reset flags each replay (stream-ordered)
    if (b == 0 && t == 65) *scandone = 0;
  }
}

// ---------------------------------------------------------------------------
// Node 2: 410 small blocks (8.7KB LDS, ~60 VGPR -> all resident, high occ).
//  scan blocks (0..159): scan -> publish which + release scandone ->
//                        dot-part epilogue (atomicAdd out) -> EXIT.
//  logz blocks (160..409): ONE 128-row vocab tile, B-frags straight from L2
//                          (no LDS stage, no bank conflicts) -> ticket.
//                          LAST ticket holder adds -log(partial)/NS.
// ---------------------------------------------------------------------------
__global__ __launch_bounds__(256) void workdots_kernel(
    const unsigned short* __restrict__ Hh, const unsigned short* __restrict__ Lh,
    const unsigned short* __restrict__ Gh, const float2* __restrict__ SM,
    const float* __restrict__ HU0, const float* __restrict__ LU0,
    const float* __restrict__ D0, const float2* __restrict__ S0,
    const float* __restrict__ prefB, const float* __restrict__ rd,
    int* __restrict__ whichOut,
    const unsigned* __restrict__ mbf, const float* __restrict__ vw,
    const float* __restrict__ vb, float* __restrict__ partial,
    const int* __restrict__ y, const float* __restrict__ move,
    float* __restrict__ out, int* __restrict__ logzdone,
    int* __restrict__ scandone)
{
  __shared__ float les[2048];                   // logz reduce (8 KB)
  __shared__ int whichs[T_];
  __shared__ int lastFlag;
  const int bid = blockIdx.x, t = threadIdx.x;
  const int lane = t & 63, wv = t >> 6;
  const int c16 = lane & 15, q = lane >> 4;

  if (bid < NCHAIN){
    // ---------------- scan (wave 0 only) ----------------
    if (t < 64){
      const int c = bid, b = c / NS_;
      const int l = t, t0 = l*8;

      float HU[8], LU[8], D[8], prev1[8], bias[8];
      #pragma unroll
      for (int k = 0; k < 8; k += 4){
        float4 h = *(const float4*)(HU0 + b*ST_ + t0 + k);
        float4 u = *(const float4*)(LU0 + b*ST_ + t0 + k);
        float4 d = *(const float4*)(D0  + b*ST_ + t0 + k);
        float4 bb= *(const float4*)(prefB + t0 + k);
        HU[k]=h.x; HU[k+1]=h.y; HU[k+2]=h.z; HU[k+3]=h.w;
        LU[k]=u.x; LU[k+1]=u.y; LU[k+2]=u.z; LU[k+3]=u.w;
        D[k]=d.x;  D[k+1]=d.y;  D[k+2]=d.z;  D[k+3]=d.w;
        bias[k]=bb.x; bias[k+1]=bb.y; bias[k+2]=bb.z; bias[k+3]=bb.w;
      }
      #pragma unroll
      for (int k = 0; k < 8; ++k) prev1[k] = 0.f;
      float2 s0 = S0[b];
      float S1 = s0.x, S2 = s0.y;
      float rdreg = (l < T_) ? rd[l*(B_*NS_) + c] : 0.f;

      for (int st = 0; st < T_; ++st){
        const float mean = S1 * (1.f/128.f);
        const float var  = (S2 - 128.f*mean*mean) * (1.f/127.f);
        const float sc   = 0.113f / (1e-5f + sqrtf(var));

        float cum[8]; float run = 0.f;
        #pragma unroll
        for (int k = 0; k < 8; ++k){
          float pref = fmaf(sc, HU[k], prev1[k] + bias[k]);
          run += __expf(pref);
          cum[k] = run;
        }
        float incl = run;
        DPPADD(incl, 0x111, 0xf)
        DPPADD(incl, 0x112, 0xf)
        DPPADD(incl, 0x114, 0xf)
        DPPADD(incl, 0x118, 0xf)
        DPPADD(incl, 0x142, 0xa)
        DPPADD(incl, 0x143, 0xc)
        const float total  = readlane_f(incl, 63);
        const float target = readlane_f(rdreg, st) * total;

        const bool cond = target < incl;
        const unsigned long long bal = __ballot(cond);
        const float excl = incl - run;
        int kw = 7; float dcand = D[7];
        #pragma unroll
        for (int k = 6; k >= 0; --k){
          bool ck = target < excl + cum[k];
          kw = ck ? k : kw;
          dcand = ck ? D[k] : dcand;
        }
        int which; float dW;
        if (bal){
          const int wlane = __ffsll(bal) - 1;
          which = __builtin_amdgcn_readlane(t0 + kw, wlane);
          dW    = readlane_f(dcand, wlane);
        } else {
          which = 0;
          dW    = readlane_f(D[0], 0);
        }
        if (l == 0){ whichs[st] = which; whichOut[c*T_ + st] = which; }

        const int rb = which*ST_ + t0;
        const uint4 hq = *(const uint4*)(Hh + rb);
        const uint4 lq = *(const uint4*)(Lh + rb);
        const uint4 gq = *(const uint4*)(Gh + rb);
        const float2 sm = SM[which];
        const unsigned ha[4] = {hq.x, hq.y, hq.z, hq.w};
        const unsigned la[4] = {lq.x, lq.y, lq.z, lq.w};
        const unsigned ga[4] = {gq.x, gq.y, gq.z, gq.w};
        #pragma unroll
        for (int k = 0; k < 8; ++k){
          const float Hk = h2f(ha[k>>1], k&1);
          const float Lk = h2f(la[k>>1], k&1);
          const float Gk = h2f(ga[k>>1], k&1);
          const float p1 = sc * LU[k];
          HU[k] = fmaf(sc, HU[k], Hk);
          LU[k] = p1 + Lk;
          D[k]  = fmaf(sc, D[k], Gk);
          prev1[k] = p1;
        }
        S1 = fmaf(sc, S1, sm.x);
        S2 = fmaf(sc*sc, S2, fmaf(2.f*sc, dW, sm.y));
      }
    }
    __syncthreads();                        // whichs / whichOut writes done

    if (t == 0){
      __threadfence();                      // release whichOut
      __hip_atomic_fetch_add(scandone, 1, __ATOMIC_RELEASE,
                             __HIP_MEMORY_SCOPE_AGENT);
    }

    // ------- dot-part epilogue (no partial needed): all 4 waves -------
    {
      const int b = bid / NS_;
      #pragma unroll
      for (int k = 0; k < 8; ++k){
        const int st = wv*8 + k;
        const int w  = whichs[st];
        const int yr = y[b*T_ + st];
        float dot = move[w*D_ + lane]      * vw[yr*D_ + lane]
                  + move[w*D_ + 64 + lane] * vw[yr*D_ + 64 + lane];
        #pragma unroll
        for (int m = 1; m < 64; m <<= 1) dot += __shfl_xor(dot, m, 64);
        if (lane == 0)
          atomicAdd(&out[b*T_ + st], (dot + vb[yr]) * (1.f/NS_));
      }
    }
  } else {
    // -------- logz: one 128-row vocab tile, B straight from L2 --------
    const int u = bid - NCHAIN;
    const char* mb = (const char*)mbf;
    const int vbase = u*128 + wv*32;
    short8 afr[2][4];
    float vbr[2][4];
    #pragma unroll
    for (int vt = 0; vt < 2; ++vt){
      const int vr = vbase + vt*16 + c16;
      const float* wp = vw + vr*D_ + q*8;
      #pragma unroll
      for (int kk = 0; kk < 4; ++kk){
        float4 f0 = *(const float4*)(wp + kk*32);
        float4 f1 = *(const float4*)(wp + kk*32 + 4);
        short8 a;
        a[0]=(short)f2bf(f0.x); a[1]=(short)f2bf(f0.y);
        a[2]=(short)f2bf(f0.z); a[3]=(short)f2bf(f0.w);
        a[4]=(short)f2bf(f1.x); a[5]=(short)f2bf(f1.y);
        a[6]=(short)f2bf(f1.z); a[7]=(short)f2bf(f1.w);
        afr[vt][kk] = a;
      }
      #pragma unroll
      for (int r = 0; r < 4; ++r)
        vbr[vt][r] = vb[vbase + vt*16 + q*4 + r];
    }

    #pragma unroll 2
    for (int s = 0; s < 32; ++s){
      short8 bfr[4];
      #pragma unroll
      for (int kk = 0; kk < 4; ++kk){
        const int row = s*16 + c16;
        bfr[kk] = *(const short8*)(mb + row*256 + q*16 + kk*64);
      }
      float es = 0.f;
      #pragma unroll
      for (int vt = 0; vt < 2; ++vt){
        f32x4 acc = {0.f,0.f,0.f,0.f};
        #pragma unroll
        for (int kk = 0; kk < 4; ++kk)
          acc = __builtin_amdgcn_mfma_f32_16x16x32_bf16(afr[vt][kk], bfr[kk], acc, 0, 0, 0);
        #pragma unroll
        for (int r = 0; r < 4; ++r)
          es += __expf(acc[r] + vbr[vt][r]);
      }
      es += __shfl_xor(es, 16, 64);
      es += __shfl_xor(es, 32, 64);
      if (lane < 16) les[wv*512 + s*16 + lane] = es;
    }
    __syncthreads();
    #pragma unroll
    for (int i = 0; i < 2; ++i){
      const int st = t + i*256;
      atomicAdd(&partial[st], les[st] + les[512+st] + les[1024+st] + les[1536+st]);
    }
    __syncthreads();

    // ---- ticket: last finisher does the -log(partial) epilogue ----
    if (t == 0){
      const int ticket = __hip_atomic_fetch_add(logzdone, 1, __ATOMIC_ACQ_REL,
                                                __HIP_MEMORY_SCOPE_AGENT);
      lastFlag = (ticket == NLOGZ - 1);
    }
    __syncthreads();
    if (lastFlag){
      if (t == 0){
        while (__hip_atomic_load(scandone, __ATOMIC_RELAXED,
                                 __HIP_MEMORY_SCOPE_AGENT) < NCHAIN)
          __builtin_amdgcn_s_sleep(8);
      }
      __syncthreads();
      __builtin_amdgcn_fence(__ATOMIC_ACQUIRE, "agent");
      for (int p = t; p < B_*T_; p += 256){
        const int b = p >> 5, st = p & 31;
        float ls = 0.f;
        #pragma unroll
        for (int s = 0; s < NS_; ++s)
          ls += __logf(partial[whichOut[(b*NS_ + s)*T_ + st]]);
        atomicAdd(&out[b*T_ + st], -ls * (1.f/NS_));
      }
    }
  }
}

extern "C" void kernel_launch(void* const* d_in, const int* in_sizes, int n_in,
                              void* d_out, int out_size, void* d_ws, size_t ws_size,
                              hipStream_t stream)
{
  const int*   zi     = (const int*)d_in[0];
  const int*   y      = (const int*)d_in[1];
  const float* rd     = (const float*)d_in[2];
  const float* latent = (const float*)d_in[3];
  const float* prefW  = (const float*)d_in[4];
  const float* prefB  = (const float*)d_in[5];
  const float* move   = (const float*)d_in[6];
  const float* vw     = (const float*)d_in[7];
  const float* vb     = (const float*)d_in[8];
  float* out = (float*)d_out;

  char* ws = (char*)d_ws;
  unsigned short* Hh = (unsigned short*)(ws);           // 512 KB
  unsigned short* Lh = (unsigned short*)(ws + 524288);  // 512 KB
  unsigned short* Gh = (unsigned short*)(ws + 1048576); // 512 KB
  float2* SM    = (float2*)(ws + 1572864);              // 4 KB
  float*  HU0   = (float*)(ws + 1576960);               // 32 KB
  float*  LU0   = (float*)(ws + 1609728);               // 32 KB
  float*  D0    = (float*)(ws + 1642496);               // 32 KB
  float2* S0    = (float2*)(ws + 1675264);              // 128 B
  float*  partial = (float*)(ws + 1675392);             // 2 KB
  int*    which = (int*)(ws + 1677440);                 // 20 KB
  unsigned* mbf = (unsigned*)(ws + 1697920);            // 128 KB (bf16 move)
  int*    logzdone = (int*)(ws + 1828992);              // flags
  int*    scandone = (int*)(ws + 1828996);

  hipLaunchKernelGGL(prep_kernel, dim3(208), dim3(256), 0, stream,
                     zi, latent, prefW, move, Hh, Lh, Gh,
                     HU0, LU0, D0, S0, SM, mbf, partial, out,
                     logzdone, scandone);
  hipLaunchKernelGGL(workdots_kernel, dim3(NBLK2), dim3(256), 0, stream,
                     Hh, Lh, Gh, SM, HU0, LU0, D0, S0, prefB, rd, which,
                     mbf, vw, vb, partial, y, move, out, logzdone, scandone);
}

// Round 15
// 73.085 us; speedup vs baseline: 2.9990x; 1.0249x over previous
//
#include <hip/hip_runtime.h>
#include <hip/hip_bf16.h>

#define B_ 16
#define T_ 32
#define NS_ 10
#define D_ 128
#define ST_ 512
#define V_ 32000
#define NCHAIN 160
#define NLOGZ 250                // one 128-row vocab tile per logz block
#define NBLK2 (NCHAIN + NLOGZ)   // 410 blocks, ~12KB LDS each -> all resident

using short8  = __attribute__((ext_vector_type(8))) short;
using f32x4   = __attribute__((ext_vector_type(4))) float;
using fvec4   = __attribute__((ext_vector_type(4))) float;   // for nontemporal builtin
using half8   = __attribute__((ext_vector_type(8))) _Float16;
using half2v  = __attribute__((ext_vector_type(2))) _Float16;

__device__ __forceinline__ unsigned short f2bf(float f){
  unsigned u = __float_as_uint(f);
  u += 0x7FFFu + ((u >> 16) & 1u);          // RNE to bf16
  return (unsigned short)(u >> 16);
}
__device__ __forceinline__ unsigned packbf(float a, float b){
  return ((unsigned)f2bf(b) << 16) | (unsigned)f2bf(a);
}
__device__ __forceinline__ unsigned short f2h(float f){
  return __builtin_bit_cast(unsigned short, (_Float16)f);
}
__device__ __forceinline__ float h2f(unsigned u, int hi){
  half2v h = __builtin_bit_cast(half2v, u);
  return (float)h[hi];
}
__device__ __forceinline__ float readlane_f(float v, int lane){
  return __int_as_float(__builtin_amdgcn_readlane(__float_as_int(v), lane));
}

// wave64 inclusive scan via DPP: 6 ops
#define DPPADD(x, ctrl, rm) { \
  int _t = __builtin_amdgcn_update_dpp(0, __float_as_int(x), ctrl, rm, 0xf, true); \
  x += __int_as_float(_t); }

// ---------------------------------------------------------------------------
// Fused scan table: row w = 64 lanes x 64B. Lane l: H (16B) | L (16B) | G (16B)
// | pad. One cache line per lane per scan step (was 3 lines across 3 tables).
// ---------------------------------------------------------------------------

// Node 1: prep. 208 blocks x 256 thr.
__global__ __launch_bounds__(256) void prep_kernel(
    const int* __restrict__ zi, const float* __restrict__ latent,
    const float* __restrict__ prefW, const float* __restrict__ move,
    unsigned short* __restrict__ fused,
    float* __restrict__ HU0, float* __restrict__ LU0, float* __restrict__ D0,
    float2* __restrict__ S0, float2* __restrict__ SM,
    unsigned* __restrict__ mbf, float* __restrict__ partial,
    float* __restrict__ out, int* __restrict__ logzdone,
    int* __restrict__ scandone)
{
  const int bid = blockIdx.x, t = threadIdx.x;
  const int lane = t & 63, wv = t >> 6;
  const int c16 = lane & 15, q = lane >> 4;

  if (bid < 192){
    const int sg = bid / 24, tile = bid % 24;
    half8 afr[4][4];
    #pragma unroll
    for (int rt = 0; rt < 4; ++rt){
      const float* mp = move + (sg*64 + rt*16 + c16)*D_ + q*8;
      #pragma unroll
      for (int kk = 0; kk < 4; ++kk){
        float4 f0 = *(const float4*)(mp + kk*32);
        float4 f1 = *(const float4*)(mp + kk*32 + 4);
        half8 a;
        a[0]=(_Float16)f0.x; a[1]=(_Float16)f0.y; a[2]=(_Float16)f0.z; a[3]=(_Float16)f0.w;
        a[4]=(_Float16)f1.x; a[5]=(_Float16)f1.y; a[6]=(_Float16)f1.z; a[7]=(_Float16)f1.w;
        afr[rt][kk] = a;
      }
    }
    const int ct = tile*64 + wv*16 + c16;     // 64-tiles never straddle 512-bounds
    const float* bp; int sect, ccol;
    if (ct < 512)      { bp = prefW + ct*256 + 128; sect = 0; ccol = ct; }
    else if (ct < 1024){ bp = prefW + (ct-512)*256; sect = 1; ccol = ct-512; }
    else               { bp = move + (ct-1024)*128; sect = 2; ccol = ct-1024; }
    half8 bfr[4];
    #pragma unroll
    for (int kk = 0; kk < 4; ++kk){
      float4 f0 = *(const float4*)(bp + q*8 + kk*32);
      float4 f1 = *(const float4*)(bp + q*8 + kk*32 + 4);
      half8 bb;
      bb[0]=(_Float16)f0.x; bb[1]=(_Float16)f0.y; bb[2]=(_Float16)f0.z; bb[3]=(_Float16)f0.w;
      bb[4]=(_Float16)f1.x; bb[5]=(_Float16)f1.y; bb[6]=(_Float16)f1.z; bb[7]=(_Float16)f1.w;
      bfr[kk] = bb;
    }
    const int foff = ((ccol >> 3) << 5) + sect*8 + (ccol & 7);
    #pragma unroll
    for (int rt = 0; rt < 4; ++rt){
      f32x4 acc = {0.f,0.f,0.f,0.f};
      #pragma unroll
      for (int kk = 0; kk < 4; ++kk)
        acc = __builtin_amdgcn_mfma_f32_16x16x32_f16(afr[rt][kk], bfr[kk], acc, 0, 0, 0);
      #pragma unroll
      for (int r = 0; r < 4; ++r){
        const int w = sg*64 + rt*16 + q*4 + r;
        fused[w*2048 + foff] = f2h(acc[r]);
      }
    }
  } else {
    const int b = bid - 192;
    __shared__ float zl[128];
    if (t < 128) zl[t] = latent[zi[b]*D_ + t];
    __syncthreads();

    #pragma unroll
    for (int ii = 0; ii < 2; ++ii){
      const int sidx = t + ii*256;
      const float* wr = prefW + sidx*256;
      const float* mv = move + sidx*128;
      float hu = 0.f, lu = 0.f, d0 = 0.f;
      #pragma unroll 8
      for (int j = 0; j < 128; j += 4){
        float4 w0 = *(const float4*)(wr + j);
        float4 w1 = *(const float4*)(wr + 128 + j);
        float4 m  = *(const float4*)(mv + j);
        float4 z  = *(const float4*)(&zl[j]);
        lu += w0.x*z.x + w0.y*z.y + w0.z*z.z + w0.w*z.w;
        hu += w1.x*z.x + w1.y*z.y + w1.z*z.z + w1.w*z.w;
        d0 += m.x*z.x + m.y*z.y + m.z*z.z + m.w*z.w;
      }
      HU0[b*ST_ + sidx] = hu; LU0[b*ST_ + sidx] = lu; D0[b*ST_ + sidx] = d0;
    }
    if (t < 64){
      float a = zl[t], bb = zl[t + 64];
      float s1 = a + bb, s2 = a*a + bb*bb;
      #pragma unroll
      for (int m = 1; m < 64; m <<= 1){ s1 += __shfl_xor(s1, m, 64); s2 += __shfl_xor(s2, m, 64); }
      if (t == 0) S0[b] = make_float2(s1, s2);
    }
    { // SM + mbf: row = b*32 + (t>>3), 8 threads/row, 16 cols each
      const int w = b*32 + (t >> 3);
      const float* mw = move + w*128 + (t & 7)*16;
      float4 m0 = *(const float4*)(mw),   m1 = *(const float4*)(mw+4);
      float4 m2 = *(const float4*)(mw+8), m3 = *(const float4*)(mw+12);
      float s1 = m0.x+m0.y+m0.z+m0.w + m1.x+m1.y+m1.z+m1.w
               + m2.x+m2.y+m2.z+m2.w + m3.x+m3.y+m3.z+m3.w;
      float s2 = m0.x*m0.x+m0.y*m0.y+m0.z*m0.z+m0.w*m0.w
               + m1.x*m1.x+m1.y*m1.y+m1.z*m1.z+m1.w*m1.w
               + m2.x*m2.x+m2.y*m2.y+m2.z*m2.z+m2.w*m2.w
               + m3.x*m3.x+m3.y*m3.y+m3.z*m3.z+m3.w*m3.w;
      #pragma unroll
      for (int m = 1; m < 8; m <<= 1){ s1 += __shfl_xor(s1, m, 64); s2 += __shfl_xor(s2, m, 64); }
      if ((t & 7) == 0) SM[w] = make_float2(s1, s2);
      unsigned* dst = mbf + w*64 + (t & 7)*8;
      dst[0] = packbf(m0.x,m0.y); dst[1] = packbf(m0.z,m0.w);
      dst[2] = packbf(m1.x,m1.y); dst[3] = packbf(m1.z,m1.w);
      dst[4] = packbf(m2.x,m2.y); dst[5] = packbf(m2.z,m2.w);
      dst[6] = packbf(m3.x,m3.y); dst[7] = packbf(m3.z,m3.w);
    }
    if (t < 32){ partial[b*32 + t] = 0.f; out[b*32 + t] = 0.f; }
    if (b == 0 && t == 64) *logzdone = 0;   // reset flags each replay (stream-ordered)
    if (b == 0 && t == 65) *scandone = 0;
  }
}

// ---------------------------------------------------------------------------
// Node 2: 410 blocks.
//  scan blocks (0..159): wave0 scans (fused 1-line gather, SM from LDS,
//    setprio 1); waves 1-3 warm this XCD's L2 with the fused table slice
//    (bid%8 = XCD, bid/8 = slice). Then publish scandone + dot-part epilogue.
//  logz blocks (160..409): one 128-row vocab tile, nontemporal vw loads,
//    B straight from L2 -> ticket; LAST adds -log(partial)/NS.
// ---------------------------------------------------------------------------
__global__ __launch_bounds__(256) void workdots_kernel(
    const unsigned short* __restrict__ fused, const float2* __restrict__ SMg,
    const float* __restrict__ HU0, const float* __restrict__ LU0,
    const float* __restrict__ D0, const float2* __restrict__ S0,
    const float* __restrict__ prefB, const float* __restrict__ rd,
    int* __restrict__ whichOut,
    const unsigned* __restrict__ mbf, const float* __restrict__ vw,
    const float* __restrict__ vb, float* __restrict__ partial,
    const int* __restrict__ y, const float* __restrict__ move,
    float* __restrict__ out, int* __restrict__ logzdone,
    int* __restrict__ scandone)
{
  __shared__ float les[2048];                   // logz reduce (8 KB)
  __shared__ float2 sml[ST_];                   // SM staged (4 KB, scan path)
  __shared__ int whichs[T_];
  __shared__ int lastFlag;
  const int bid = blockIdx.x, t = threadIdx.x;
  const int lane = t & 63, wv = t >> 6;
  const int c16 = lane & 15, q = lane >> 4;

  if (bid < NCHAIN){
    // ---- stage SM -> LDS (wave 1) ----
    if (wv == 1){
      #pragma unroll
      for (int j = 0; j < 8; ++j) sml[(t - 64)*8 + j] = SMg[(t - 64)*8 + j];
    }
    __syncthreads();

    if (t < 64){
      // ---------------- scan (wave 0) ----------------
      const int c = bid, b = c / NS_;
      const int l = t, t0 = l*8;

      float HU[8], LU[8], D[8], prev1[8], bias[8];
      #pragma unroll
      for (int k = 0; k < 8; k += 4){
        float4 h = *(const float4*)(HU0 + b*ST_ + t0 + k);
        float4 u = *(const float4*)(LU0 + b*ST_ + t0 + k);
        float4 d = *(const float4*)(D0  + b*ST_ + t0 + k);
        float4 bb= *(const float4*)(prefB + t0 + k);
        HU[k]=h.x; HU[k+1]=h.y; HU[k+2]=h.z; HU[k+3]=h.w;
        LU[k]=u.x; LU[k+1]=u.y; LU[k+2]=u.z; LU[k+3]=u.w;
        D[k]=d.x;  D[k+1]=d.y;  D[k+2]=d.z;  D[k+3]=d.w;
        bias[k]=bb.x; bias[k+1]=bb.y; bias[k+2]=bb.z; bias[k+3]=bb.w;
      }
      #pragma unroll
      for (int k = 0; k < 8; ++k) prev1[k] = 0.f;
      float2 s0 = S0[b];
      float S1 = s0.x, S2 = s0.y;
      float rdreg = (l < T_) ? rd[l*(B_*NS_) + c] : 0.f;

      __builtin_amdgcn_s_setprio(1);
      for (int st = 0; st < T_; ++st){
        const float mean = S1 * (1.f/128.f);
        const float var  = (S2 - 128.f*mean*mean) * (1.f/127.f);
        const float sc   = 0.113f / (1e-5f + sqrtf(var));

        float cum[8]; float run = 0.f;
        #pragma unroll
        for (int k = 0; k < 8; ++k){
          float pref = fmaf(sc, HU[k], prev1[k] + bias[k]);
          run += __expf(pref);
          cum[k] = run;
        }
        float incl = run;
        DPPADD(incl, 0x111, 0xf)
        DPPADD(incl, 0x112, 0xf)
        DPPADD(incl, 0x114, 0xf)
        DPPADD(incl, 0x118, 0xf)
        DPPADD(incl, 0x142, 0xa)
        DPPADD(incl, 0x143, 0xc)
        const float total  = readlane_f(incl, 63);
        const float target = readlane_f(rdreg, st) * total;

        const bool cond = target < incl;
        const unsigned long long bal = __ballot(cond);
        const float excl = incl - run;
        int kw = 7; float dcand = D[7];
        #pragma unroll
        for (int k = 6; k >= 0; --k){
          bool ck = target < excl + cum[k];
          kw = ck ? k : kw;
          dcand = ck ? D[k] : dcand;
        }
        int which; float dW;
        if (bal){
          const int wlane = __ffsll(bal) - 1;
          which = __builtin_amdgcn_readlane(t0 + kw, wlane);
          dW    = readlane_f(dcand, wlane);
        } else {
          which = 0;
          dW    = readlane_f(D[0], 0);
        }
        if (l == 0){ whichs[st] = which; whichOut[c*T_ + st] = which; }

        // fused gather: one 64B line per lane (H|L|G), SM from LDS
        const char* fp = (const char*)fused + ((unsigned)which << 12) + (unsigned)(l << 6);
        const uint4 hq = *(const uint4*)(fp);
        const uint4 lq = *(const uint4*)(fp + 16);
        const uint4 gq = *(const uint4*)(fp + 32);
        const float2 sm = sml[which];
        const unsigned ha[4] = {hq.x, hq.y, hq.z, hq.w};
        const unsigned la[4] = {lq.x, lq.y, lq.z, lq.w};
        const unsigned ga[4] = {gq.x, gq.y, gq.z, gq.w};
        #pragma unroll
        for (int k = 0; k < 8; ++k){
          const float Hk = h2f(ha[k>>1], k&1);
          const float Lk = h2f(la[k>>1], k&1);
          const float Gk = h2f(ga[k>>1], k&1);
          const float p1 = sc * LU[k];
          HU[k] = fmaf(sc, HU[k], Hk);
          LU[k] = p1 + Lk;
          D[k]  = fmaf(sc, D[k], Gk);
          prev1[k] = p1;
        }
        S1 = fmaf(sc, S1, sm.x);
        S2 = fmaf(sc*sc, S2, fmaf(2.f*sc, dW, sm.y));
      }
      __builtin_amdgcn_s_setprio(0);
    } else {
      // ---- waves 1-3: warm the fused table into this XCD's L2 ----
      const float* fb = (const float*)fused;
      const int slice = bid >> 3;               // 20 blocks per XCD (bid%8)
      const int r0 = slice*26;
      const int r1 = (r0 + 26 < 512) ? (r0 + 26) : 512;
      float acc = 0.f;
      for (int r = r0; r < r1; ++r){
        for (int off = (t - 64)*4; off < 1024; off += 192*4){
          fvec4 v = *(const fvec4*)(fb + (unsigned)r*1024 + off);
          acc += v[0] + v[1] + v[2] + v[3];
        }
      }
      asm volatile("" :: "v"(acc));             // keep loads live (no DCE)
    }
    __syncthreads();                        // whichs / whichOut writes done

    if (t == 0){
      __threadfence();                      // release whichOut
      __hip_atomic_fetch_add(scandone, 1, __ATOMIC_RELEASE,
                             __HIP_MEMORY_SCOPE_AGENT);
    }

    // ------- dot-part epilogue (no partial needed): all 4 waves -------
    {
      const int b = bid / NS_;
      #pragma unroll
      for (int k = 0; k < 8; ++k){
        const int st = wv*8 + k;
        const int w  = whichs[st];
        const int yr = y[b*T_ + st];
        float dot = move[w*D_ + lane]      * vw[yr*D_ + lane]
                  + move[w*D_ + 64 + lane] * vw[yr*D_ + 64 + lane];
        #pragma unroll
        for (int m = 1; m < 64; m <<= 1) dot += __shfl_xor(dot, m, 64);
        if (lane == 0)
          atomicAdd(&out[b*T_ + st], (dot + vb[yr]) * (1.f/NS_));
      }
    }
  } else {
    // -------- logz: one 128-row vocab tile, nontemporal vw reads --------
    const int u = bid - NCHAIN;
    const char* mb = (const char*)mbf;
    const int vbase = u*128 + wv*32;
    short8 afr[2][4];
    float vbr[2][4];
    #pragma unroll
    for (int vt = 0; vt < 2; ++vt){
      const int vr = vbase + vt*16 + c16;
      const float* wp = vw + vr*D_ + q*8;
      #pragma unroll
      for (int kk = 0; kk < 4; ++kk){
        fvec4 f0 = __builtin_nontemporal_load((const fvec4*)(wp + kk*32));
        fvec4 f1 = __builtin_nontemporal_load((const fvec4*)(wp + kk*32 + 4));
        short8 a;
        a[0]=(short)f2bf(f0[0]); a[1]=(short)f2bf(f0[1]);
        a[2]=(short)f2bf(f0[2]); a[3]=(short)f2bf(f0[3]);
        a[4]=(short)f2bf(f1[0]); a[5]=(short)f2bf(f1[1]);
        a[6]=(short)f2bf(f1[2]); a[7]=(short)f2bf(f1[3]);
        afr[vt][kk] = a;
      }
      #pragma unroll
      for (int r = 0; r < 4; ++r)
        vbr[vt][r] = vb[vbase + vt*16 + q*4 + r];
    }

    #pragma unroll 2
    for (int s = 0; s < 32; ++s){
      short8 bfr[4];
      #pragma unroll
      for (int kk = 0; kk < 4; ++kk){
        const int row = s*16 + c16;
        bfr[kk] = *(const short8*)(mb + row*256 + q*16 + kk*64);
      }
      float es = 0.f;
      #pragma unroll
      for (int vt = 0; vt < 2; ++vt){
        f32x4 acc = {0.f,0.f,0.f,0.f};
        #pragma unroll
        for (int kk = 0; kk < 4; ++kk)
          acc = __builtin_amdgcn_mfma_f32_16x16x32_bf16(afr[vt][kk], bfr[kk], acc, 0, 0, 0);
        #pragma unroll
        for (int r = 0; r < 4; ++r)
          es += __expf(acc[r] + vbr[vt][r]);
      }
      es += __shfl_xor(es, 16, 64);
      es += __shfl_xor(es, 32, 64);
      if (lane < 16) les[wv*512 + s*16 + lane] = es;
    }
    __syncthreads();
    #pragma unroll
    for (int i = 0; i < 2; ++i){
      const int st = t + i*256;
      atomicAdd(&partial[st], les[st] + les[512+st] + les[1024+st] + les[1536+st]);
    }
    __syncthreads();

    // ---- ticket: last finisher does the -log(partial) epilogue ----
    if (t == 0){
      const int ticket = __hip_atomic_fetch_add(logzdone, 1, __ATOMIC_ACQ_REL,
                                                __HIP_MEMORY_SCOPE_AGENT);
      lastFlag = (ticket == NLOGZ - 1);
    }
    __syncthreads();
    if (lastFlag){
      if (t == 0){
        while (__hip_atomic_load(scandone, __ATOMIC_RELAXED,
                                 __HIP_MEMORY_SCOPE_AGENT) < NCHAIN)
          __builtin_amdgcn_s_sleep(8);
      }
      __syncthreads();
      __builtin_amdgcn_fence(__ATOMIC_ACQUIRE, "agent");
      for (int p = t; p < B_*T_; p += 256){
        const int b = p >> 5, st = p & 31;
        float ls = 0.f;
        #pragma unroll
        for (int s = 0; s < NS_; ++s)
          ls += __logf(partial[whichOut[(b*NS_ + s)*T_ + st]]);
        atomicAdd(&out[b*T_ + st], -ls * (1.f/NS_));
      }
    }
  }
}

extern "C" void kernel_launch(void* const* d_in, const int* in_sizes, int n_in,
                              void* d_out, int out_size, void* d_ws, size_t ws_size,
                              hipStream_t stream)
{
  const int*   zi     = (const int*)d_in[0];
  const int*   y      = (const int*)d_in[1];
  const float* rd     = (const float*)d_in[2];
  const float* latent = (const float*)d_in[3];
  const float* prefW  = (const float*)d_in[4];
  const float* prefB  = (const float*)d_in[5];
  const float* move   = (const float*)d_in[6];
  const float* vw     = (const float*)d_in[7];
  const float* vb     = (const float*)d_in[8];
  float* out = (float*)d_out;

  char* ws = (char*)d_ws;
  unsigned short* fused = (unsigned short*)(ws);        // 2 MB (512 x 4KB rows)
  float2* SM    = (float2*)(ws + 2097152);              // 4 KB
  float*  HU0   = (float*)(ws + 2101248);               // 32 KB
  float*  LU0   = (float*)(ws + 2134016);               // 32 KB
  float*  D0    = (float*)(ws + 2166784);               // 32 KB
  float2* S0    = (float2*)(ws + 2199552);              // 128 B
  float*  partial = (float*)(ws + 2199680);             // 2 KB
  int*    which = (int*)(ws + 2201728);                 // 20 KB
  unsigned* mbf = (unsigned*)(ws + 2222208);            // 128 KB (bf16 move)
  int*    logzdone = (int*)(ws + 2353280);              // flags
  int*    scandone = (int*)(ws + 2353284);

  hipLaunchKernelGGL(prep_kernel, dim3(208), dim3(256), 0, stream,
                     zi, latent, prefW, move, fused,
                     HU0, LU0, D0, S0, SM, mbf, partial, out,
                     logzdone, scandone);
  hipLaunchKernelGGL(workdots_kernel, dim3(NBLK2), dim3(256), 0, stream,
                     fused, SM, HU0, LU0, D0, S0, prefB, rd, which,
                     mbf, vw, vb, partial, y, move, out, logzdone, scandone);
}